// Round 5
// baseline (1184.793 us; speedup 1.0000x reference)
//
#include <hip/hip_runtime.h>
#include <hip/hip_bf16.h>

// Problem constants
#define B_ 64
#define S_ 128
#define C_ 32
#define D_ 512
#define V_ 20000

typedef __bf16  bf16x8 __attribute__((ext_vector_type(8)));
typedef float   f32x4  __attribute__((ext_vector_type(4)));
typedef __fp16  v2h    __attribute__((ext_vector_type(2)));

// ---- workspace layout (bytes) ----
#define OFF_XBF  0ull          // bf16 x   [8192][512]   8,388,608
#define OFF_UBF  8388608ull    // bf16 U   [2048][512]   2,097,152
#define OFF_WG   10485760ull   // fp16 W_all [2048][512] 2,097,152 (plain row-major)
#define OFF_WD   12582912ull   // fp16 W_d [512][512]      524,288 (plain row-major)
#define OFF_CB   13107200ull   // f32 cb[2048]               8,192
#define OFF_SYNC 13115392ull   // int flags[32][8] @0 ; f32 pooled_red[128] @4096 ; pad 8KB
#define OFF_XB   13123584ull   // fp16 xbuf[2][32][8][256] = 262,144 (per-member contiguous)
#define OFF_TF   13385728ull   // fp16 tf [8192][512]    8,388,608
#define OFF_UX   21774336ull   // fp16 ux [8192][2048]  33,554,432   -> total ~55.3 MB

// ---------------- zero kernel (flags + pooled_red only) ----------------
__global__ void k_zero(int4* __restrict__ p)
{
    p[blockIdx.x * 256 + threadIdx.x] = int4{0, 0, 0, 0};
}

// ---------------- prep kernels ----------------
__global__ void k_prep_wall(const float* __restrict__ W, _Float16* __restrict__ o)
{
    int i = blockIdx.x * 256 + threadIdx.x;      // 0 .. 1048575
    o[i] = (_Float16)W[i];
}

__global__ void k_prep_wd(const float* __restrict__ W, _Float16* __restrict__ o)
{
    int i = blockIdx.x * 256 + threadIdx.x;      // 0 .. 262143
    o[i] = (_Float16)W[i];
}

__global__ void k_prep_u(const float* __restrict__ U, __hip_bfloat16* __restrict__ o)
{
    int i = blockIdx.x * 256 + threadIdx.x;      // 0 .. 1048575
    o[i] = __float2bfloat16(U[i]);
}

__global__ void k_prep_cb(const float* __restrict__ a, const float* __restrict__ b,
                          float* __restrict__ o)
{
    int i = blockIdx.x * 256 + threadIdx.x;      // 0 .. 2047
    o[i] = a[i] + b[i];
}

// ---------------- embedding gather-sum -> x bf16 ----------------
__global__ void k_embed(const float* __restrict__ emb, const int* __restrict__ seqs,
                        __hip_bfloat16* __restrict__ xbf)
{
    int bs = blockIdx.x;           // b*S + s
    int t  = threadIdx.x;          // 256 threads, 2 floats each
    const int* ip = seqs + (size_t)bs * C_;
    float ax = 0.f, ay = 0.f;
    for (int c = 0; c < C_; c++) {
        int row = ip[c];
        if (row < 0) row = V_;
        const float2 v = *(const float2*)(emb + (size_t)row * D_ + 2 * t);
        ax += v.x; ay += v.y;
    }
    xbf[(size_t)bs * D_ + 2 * t]     = __float2bfloat16(ax);
    xbf[(size_t)bs * D_ + 2 * t + 1] = __float2bfloat16(ay);
}

// ---------------- time feature -> tf fp16 [8192][512] ----------------
__global__ void k_tf(const float* __restrict__ stime, const float* __restrict__ selw,
                     const float* __restrict__ selb, const float* __restrict__ timew,
                     const float* __restrict__ timeb, _Float16* __restrict__ tf)
{
    int bs = blockIdx.x;
    int t  = threadIdx.x;          // 128
    __shared__ float s1[64];
    float tv = stime[bs] * (1.0f / 180.0f);
    if (t < 64) {
        float u = tv * selw[t] + selb[t];
        s1[t] = 1.0f - tanhf(u * u);
    }
    __syncthreads();
    for (int d = t; d < D_; d += 128) {
        float a = timeb[d];
        const float* wr = timew + (size_t)d * 64;
        #pragma unroll 8
        for (int j = 0; j < 64; j++) a += s1[j] * wr[j];
        tf[(size_t)bs * D_ + d] = (_Float16)a;
    }
}

// ---------------- ux GEMM: [8192][512]bf16 x [2048][512]bf16^T -> [8192][2048]fp16 ----
__global__ __launch_bounds__(512) void k_gemm(const __bf16* __restrict__ A,
                                              const __bf16* __restrict__ Bm,
                                              _Float16* __restrict__ Cg)
{
    int lane = threadIdx.x & 63;
    int w    = threadIdx.x >> 6;     // 8 waves
    int wm = w & 3, wn = w >> 2;     // wave tile 32x64
    int q = lane >> 4, r = lane & 15;
    int m0 = blockIdx.y * 128 + wm * 32;
    int n0 = blockIdx.x * 128 + wn * 64;

    const __bf16* pa0 = A  + (size_t)(m0 + r) * 512 + q * 8;
    const __bf16* pa1 = pa0 + (size_t)16 * 512;
    const __bf16* pb  = Bm + (size_t)(n0 + r) * 512 + q * 8;

    f32x4 acc[2][4] = {};
    for (int k = 0; k < 512; k += 32) {
        bf16x8 a0 = *(const bf16x8*)(pa0 + k);
        bf16x8 a1 = *(const bf16x8*)(pa1 + k);
        bf16x8 b0 = *(const bf16x8*)(pb + k);
        bf16x8 b1 = *(const bf16x8*)(pb + (size_t)16 * 512 + k);
        bf16x8 b2 = *(const bf16x8*)(pb + (size_t)32 * 512 + k);
        bf16x8 b3 = *(const bf16x8*)(pb + (size_t)48 * 512 + k);
        acc[0][0] = __builtin_amdgcn_mfma_f32_16x16x32_bf16(a0, b0, acc[0][0], 0, 0, 0);
        acc[0][1] = __builtin_amdgcn_mfma_f32_16x16x32_bf16(a0, b1, acc[0][1], 0, 0, 0);
        acc[0][2] = __builtin_amdgcn_mfma_f32_16x16x32_bf16(a0, b2, acc[0][2], 0, 0, 0);
        acc[0][3] = __builtin_amdgcn_mfma_f32_16x16x32_bf16(a0, b3, acc[0][3], 0, 0, 0);
        acc[1][0] = __builtin_amdgcn_mfma_f32_16x16x32_bf16(a1, b0, acc[1][0], 0, 0, 0);
        acc[1][1] = __builtin_amdgcn_mfma_f32_16x16x32_bf16(a1, b1, acc[1][1], 0, 0, 0);
        acc[1][2] = __builtin_amdgcn_mfma_f32_16x16x32_bf16(a1, b2, acc[1][2], 0, 0, 0);
        acc[1][3] = __builtin_amdgcn_mfma_f32_16x16x32_bf16(a1, b3, acc[1][3], 0, 0, 0);
    }
    for (int am = 0; am < 2; am++)
        for (int bn = 0; bn < 4; bn++) {
            int row = m0 + am * 16 + q * 4;
            int col = n0 + bn * 16 + r;
            _Float16* cp = Cg + (size_t)row * 2048 + col;
            #pragma unroll
            for (int t = 0; t < 4; t++) cp[(size_t)t * 2048] = (_Float16)acc[am][bn][t];
        }
}

// ---------------- recurrence helpers ----------------
__device__ __forceinline__ float dp2(int h, int w, float acc)
{
#if __has_builtin(__builtin_amdgcn_fdot2)
    return __builtin_amdgcn_fdot2(__builtin_bit_cast(v2h, h),
                                  __builtin_bit_cast(v2h, w), acc, false);
#else
    v2h a = __builtin_bit_cast(v2h, h), b = __builtin_bit_cast(v2h, w);
    return acc + (float)a.x * (float)b.x + (float)a.y * (float)b.y;
#endif
}

__device__ __forceinline__ float dot8(int4 h, int4 w, float acc)
{
    acc = dp2(h.x, w.x, acc);
    acc = dp2(h.y, w.y, acc);
    acc = dp2(h.z, w.z, acc);
    acc = dp2(h.w, w.w, acc);
    return acc;
}

// ---------------- recurrence: 32 groups x 8 blocks, weights in VGPRs -------------
// Group gid = bid>>3, batches {2gid, 2gid+1}. Member m = bid&7 owns d-slice m*64.
// Exchange: xb[par][gid][member][256 fp16] — per-member CONTIGUOUS 512 B slice
// (payload order: lane l of publisher wave -> b=l>>5, hc=(l>>4)&1, dl4=(l&15)*4).
// Consumer wave w handles member w: spins on flags[gid*8+w] (no s_sleep), then
// loads that slice and stages to LDS — detection/fetch overlap across members,
// and wave 0's publish drain overlaps the other waves' polling.
__global__ __launch_bounds__(512, 2) void k_rnn5(
    const _Float16* __restrict__ Wg, const _Float16* __restrict__ Wd,
    const float* __restrict__ cbv, const float* __restrict__ wdb,
    const _Float16* __restrict__ ux, const _Float16* __restrict__ tf,
    const float* __restrict__ outw,
    int* __restrict__ flags, float* __restrict__ pooled_red,
    _Float16* __restrict__ xb)
{
    const int t    = threadIdx.x;
    const int gid  = blockIdx.x >> 3;
    const int m    = blockIdx.x & 7;
    const int d0   = m * 64;
    const int b0   = gid * 2;
    const int rr   = t >> 3;           // 0..63 local d
    const int q8   = t & 7;            // k-eighth
    const int w    = t >> 6;           // wave id = consumed member id
    const int lane = t & 63;

    // ---- weights -> VGPRs (chunk order rotated by q8: conflict-free LDS reads) ----
    int4 Wf[8], Wi[8], Wo[8], Wc[8], Wdr[8];
    {
        const int4* p0 = (const int4*)(Wg + ((size_t)(0 * 512 + d0 + rr) * 512 + q8 * 64));
        const int4* p1 = (const int4*)(Wg + ((size_t)(1 * 512 + d0 + rr) * 512 + q8 * 64));
        const int4* p2 = (const int4*)(Wg + ((size_t)(2 * 512 + d0 + rr) * 512 + q8 * 64));
        const int4* p3 = (const int4*)(Wg + ((size_t)(3 * 512 + d0 + rr) * 512 + q8 * 64));
        const int4* pd = (const int4*)(Wd + ((size_t)(d0 + rr) * 512 + q8 * 64));
        #pragma unroll
        for (int i = 0; i < 8; i++) {
            int j = (i + q8) & 7;
            Wf[i] = p0[j]; Wi[i] = p1[j]; Wo[i] = p2[j]; Wc[i] = p3[j]; Wdr[i] = pd[j];
        }
    }

    __shared__ __align__(16) _Float16 hbuf[2][512];
    __shared__ __align__(16) _Float16 cbuf[2][512];
    __shared__ __align__(16) _Float16 ostg[2][2][64];   // [batch][h/c][dl]
    __shared__ float pstg[2][64];

    float c_reg[2] = {0.f, 0.f};
    float pool[2]  = {-1e30f, -1e30f};

    float cbf = 0, cbi = 0, cbo = 0, cbc = 0, bdv = 0;
    if (q8 == 0) {
        int d = d0 + rr;
        cbf = cbv[d]; cbi = cbv[512 + d]; cbo = cbv[1024 + d]; cbc = cbv[1536 + d];
        bdv = wdb[d];
    }
    int* fl = flags + gid * 8;

    // payload decode for this thread's staging role (wave w <-> member w)
    const int sb   = lane >> 5;           // batch 0/1
    const int shc  = (lane >> 4) & 1;     // 0=h, 1=c
    const int sdl4 = (lane & 15) * 4;     // 4-fp16 offset within 64-d slice

    for (int s = 0; s < S_; s++) {
        const int sp = s & 1, dpar = sp ^ 1;

        // ux/tf prefetch (independent of h; flies during the poll)
        float uf[2], ui2[2], uo[2], uc[2], tv[2];
        if (q8 == 0) {
            #pragma unroll
            for (int b = 0; b < 2; b++) {
                size_t bs = (size_t)(b0 + b) * S_ + s;
                const _Float16* up = ux + bs * 2048 + (d0 + rr);
                uf[b]  = (float)up[0];    ui2[b] = (float)up[512];
                uo[b]  = (float)up[1024]; uc[b]  = (float)up[1536];
                tv[b]  = (float)tf[bs * 512 + (d0 + rr)];
            }
        }

        // stage H_s, C_s into LDS: wave w gates on member w's flag, loads its slice
        {
            unsigned long long val = 0ull;
            if (s > 0) {
                int tries = 0;
                while (__hip_atomic_load(fl + w, __ATOMIC_RELAXED,
                                         __HIP_MEMORY_SCOPE_AGENT) < s) {
                    if (++tries > (1 << 22)) break;   // safety valve
                }
                asm volatile("" ::: "memory");        // no hoisting loads above poll
                const unsigned long long* src = (const unsigned long long*)
                    (xb + ((size_t)(sp * 32 + gid) * 8 + w) * 256 + lane * 4);
                val = __hip_atomic_load(src, __ATOMIC_RELAXED,
                                        __HIP_MEMORY_SCOPE_AGENT);
            }
            __syncthreads();             // prior step's LDS consumers done (B2)
            _Float16* dst = (shc ? cbuf[sb] : hbuf[sb]) + w * 64 + sdl4;
            *(unsigned long long*)dst = val;
        }
        __syncthreads();                 // all staged (B1)

        // dot phase: register weights x LDS h/c (rotated chunk order)
        float ag[2][4], ad[2];
        #pragma unroll
        for (int b = 0; b < 2; b++) {
            const int4* hp = (const int4*)hbuf[b] + q8 * 8;
            const int4* cp = (const int4*)cbuf[b] + q8 * 8;
            float f_ = 0, i_ = 0, o_ = 0, c_ = 0, d_ = 0;
            #pragma unroll
            for (int i = 0; i < 8; i++) {
                int j = (i + q8) & 7;
                int4 hv = hp[j];
                f_ = dot8(hv, Wf[i], f_);
                i_ = dot8(hv, Wi[i], i_);
                o_ = dot8(hv, Wo[i], o_);
                c_ = dot8(hv, Wc[i], c_);
            }
            #pragma unroll
            for (int i = 0; i < 8; i++) {
                int j = (i + q8) & 7;
                d_ = dot8(cp[j], Wdr[i], d_);
            }
            ag[b][0] = f_; ag[b][1] = i_; ag[b][2] = o_; ag[b][3] = c_; ad[b] = d_;
        }
        // reduce over the 8 k-eighth lanes
        #pragma unroll
        for (int off = 1; off < 8; off <<= 1) {
            #pragma unroll
            for (int b = 0; b < 2; b++) {
                ag[b][0] += __shfl_xor(ag[b][0], off);
                ag[b][1] += __shfl_xor(ag[b][1], off);
                ag[b][2] += __shfl_xor(ag[b][2], off);
                ag[b][3] += __shfl_xor(ag[b][3], off);
                ad[b]    += __shfl_xor(ad[b],    off);
            }
        }

        if (q8 == 0) {
            #pragma unroll
            for (int b = 0; b < 2; b++) {
                float gf = 1.f / (1.f + expf(-(ag[b][0] + cbf + uf[b])));
                float gi = 1.f / (1.f + expf(-(ag[b][1] + cbi + ui2[b])));
                float go = 1.f / (1.f + expf(-(ag[b][2] + cbo + uo[b])));
                float gc = 1.f / (1.f + expf(-(ag[b][3] + cbc + uc[b])));
                float cs1  = tanhf(ad[b] + bdv);
                float cadj = c_reg[b] - cs1 + cs1 * tv[b];
                float cn   = gf * cadj + gi * gc;
                float hn   = go * tanhf(cn);
                c_reg[b] = cn;
                pool[b]  = fmaxf(pool[b], hn);
                ostg[b][0][rr] = (_Float16)hn;
                ostg[b][1][rr] = (_Float16)cn;
            }
        }
        __syncthreads();                 // ostg complete (B2 of this step)

        // wave 0 publishes this block's contiguous 512 B slice, then the flag;
        // other waves proceed straight to the next step's poll.
        if (s != S_ - 1 && w == 0) {
            unsigned long long val = *(const unsigned long long*)&ostg[sb][shc][sdl4];
            unsigned long long* dst = (unsigned long long*)
                (xb + ((size_t)(dpar * 32 + gid) * 8 + m) * 256 + lane * 4);
            __hip_atomic_store(dst, val, __ATOMIC_RELAXED, __HIP_MEMORY_SCOPE_AGENT);
            asm volatile("s_waitcnt vmcnt(0)" ::: "memory");   // data at MALL first
            if (lane == 0)
                __hip_atomic_store(fl + m, s + 1, __ATOMIC_RELAXED,
                                   __HIP_MEMORY_SCOPE_AGENT);
        }
    }

    // pooled epilogue
    if (q8 == 0) { pstg[0][rr] = pool[0]; pstg[1][rr] = pool[1]; }
    __syncthreads();
    if (t < 128) {
        int b = t >> 6, l = t & 63;
        float pv = pstg[b][l];
        int d = d0 + l;
        float p0 = pv * outw[d], p1 = pv * outw[512 + d];
        #pragma unroll
        for (int off = 32; off > 0; off >>= 1) {
            p0 += __shfl_down(p0, off);
            p1 += __shfl_down(p1, off);
        }
        if (l == 0) {
            atomicAdd(&pooled_red[2 * (b0 + b)],     p0);
            atomicAdd(&pooled_red[2 * (b0 + b) + 1], p1);
        }
    }
}

// ---------------- final output ----------------
__global__ void k_out(const float* __restrict__ pr, const float* __restrict__ outb,
                      float* __restrict__ out)
{
    int i = threadIdx.x;
    if (i < 128) out[i] = pr[i] + outb[i & 1];
}

// ---------------- launch ----------------
extern "C" void kernel_launch(void* const* d_in, const int* in_sizes, int n_in,
                              void* d_out, int out_size, void* d_ws, size_t ws_size,
                              hipStream_t stream)
{
    const float* emb   = (const float*)d_in[0];
    const float* Wall  = (const float*)d_in[1];
    const float* Wallb = (const float*)d_in[2];
    const float* Uall  = (const float*)d_in[3];
    const float* Uallb = (const float*)d_in[4];
    const float* Wdw   = (const float*)d_in[5];
    const float* Wdb   = (const float*)d_in[6];
    const float* selw  = (const float*)d_in[7];
    const float* selb  = (const float*)d_in[8];
    const float* timew = (const float*)d_in[9];
    const float* timeb = (const float*)d_in[10];
    const float* outw  = (const float*)d_in[11];
    const float* outb  = (const float*)d_in[12];
    const float* stime = (const float*)d_in[13];
    const int*   seqs  = (const int*)d_in[14];
    float* out = (float*)d_out;
    char*  ws  = (char*)d_ws;

    __hip_bfloat16* xbf = (__hip_bfloat16*)(ws + OFF_XBF);
    __hip_bfloat16* ubf = (__hip_bfloat16*)(ws + OFF_UBF);
    _Float16* wg   = (_Float16*)(ws + OFF_WG);
    _Float16* wd   = (_Float16*)(ws + OFF_WD);
    float*    cbp  = (float*)(ws + OFF_CB);
    int*      flg  = (int*)(ws + OFF_SYNC);
    float*    pred = (float*)(ws + OFF_SYNC + 4096);
    _Float16* xb   = (_Float16*)(ws + OFF_XB);
    _Float16* tfp  = (_Float16*)(ws + OFF_TF);
    _Float16* uxp  = (_Float16*)(ws + OFF_UX);

    // zero: flags (4KB) + pooled_red + pad = 8 KB (xbuf needs no init: s=0 reads none)
    k_zero     <<<2, 256, 0, stream>>>((int4*)(ws + OFF_SYNC));
    k_prep_wall<<<4096, 256, 0, stream>>>(Wall, wg);
    k_prep_wd  <<<1024, 256, 0, stream>>>(Wdw, wd);
    k_prep_u   <<<4096, 256, 0, stream>>>(Uall, ubf);
    k_prep_cb  <<<8,    256, 0, stream>>>(Wallb, Uallb, cbp);
    k_embed    <<<B_ * S_, 256, 0, stream>>>(emb, seqs, xbf);
    k_tf       <<<B_ * S_, 128, 0, stream>>>(stime, selw, selb, timew, timeb, tfp);
    k_gemm     <<<dim3(16, 64), 512, 0, stream>>>((const __bf16*)xbf, (const __bf16*)ubf, uxp);
    k_rnn5     <<<256, 512, 0, stream>>>(wg, wd, cbp, Wdb, uxp, tfp, outw,
                                         flg, pred, xb);
    k_out      <<<1, 128, 0, stream>>>(pred, outb, out);
}

// Round 6
// 994.353 us; speedup vs baseline: 1.1915x; 1.1915x over previous
//
#include <hip/hip_runtime.h>
#include <hip/hip_bf16.h>

// Problem constants
#define B_ 64
#define S_ 128
#define C_ 32
#define D_ 512
#define V_ 20000

typedef __bf16  bf16x8 __attribute__((ext_vector_type(8)));
typedef float   f32x4  __attribute__((ext_vector_type(4)));
typedef __fp16  v2h    __attribute__((ext_vector_type(2)));

// ---- workspace layout (bytes) ----
#define OFF_XBF  0ull          // bf16 x   [8192][512]   8,388,608
#define OFF_UBF  8388608ull    // bf16 U   [2048][512]   2,097,152
#define OFF_WG   10485760ull   // fp16 W_all [2048][512] 2,097,152 (plain row-major)
#define OFF_WD   12582912ull   // fp16 W_d [512][512]      524,288 (plain row-major)
#define OFF_CB   13107200ull   // f32 cb[2048]               8,192
#define OFF_SYNC 13115392ull   // f32 pooled_red[128] @4096 ; 8 KB total
#define OFF_TF   13385728ull   // fp16 tf [8192][512]    8,388,608
#define OFF_UX   21774336ull   // fp16 ux [8192][2048]  33,554,432
#define OFF_XB2  55328768ull   // u64 xb[128][32][8][64] = 16,777,216 (self-flagging)
                               // total 72,105,984 B

#define SENT32 0x7FFF7FFFu     // two fp16 NaNs — never produced by finite (h,c) pack

// ---------------- zero kernel (pooled_red) ----------------
__global__ void k_zero(int4* __restrict__ p)
{
    p[blockIdx.x * 256 + threadIdx.x] = int4{0, 0, 0, 0};
}

// ---------------- sentinel prefill for the exchange buffer ----------------
__global__ void k_fill(int4* __restrict__ p)
{
    p[blockIdx.x * 256 + threadIdx.x] =
        int4{(int)SENT32, (int)SENT32, (int)SENT32, (int)SENT32};
}

// ---------------- prep kernels ----------------
__global__ void k_prep_wall(const float* __restrict__ W, _Float16* __restrict__ o)
{
    int i = blockIdx.x * 256 + threadIdx.x;      // 0 .. 1048575
    o[i] = (_Float16)W[i];
}

__global__ void k_prep_wd(const float* __restrict__ W, _Float16* __restrict__ o)
{
    int i = blockIdx.x * 256 + threadIdx.x;      // 0 .. 262143
    o[i] = (_Float16)W[i];
}

__global__ void k_prep_u(const float* __restrict__ U, __hip_bfloat16* __restrict__ o)
{
    int i = blockIdx.x * 256 + threadIdx.x;      // 0 .. 1048575
    o[i] = __float2bfloat16(U[i]);
}

__global__ void k_prep_cb(const float* __restrict__ a, const float* __restrict__ b,
                          float* __restrict__ o)
{
    int i = blockIdx.x * 256 + threadIdx.x;      // 0 .. 2047
    o[i] = a[i] + b[i];
}

// ---------------- embedding gather-sum -> x bf16 ----------------
__global__ void k_embed(const float* __restrict__ emb, const int* __restrict__ seqs,
                        __hip_bfloat16* __restrict__ xbf)
{
    int bs = blockIdx.x;           // b*S + s
    int t  = threadIdx.x;          // 256 threads, 2 floats each
    const int* ip = seqs + (size_t)bs * C_;
    float ax = 0.f, ay = 0.f;
    for (int c = 0; c < C_; c++) {
        int row = ip[c];
        if (row < 0) row = V_;
        const float2 v = *(const float2*)(emb + (size_t)row * D_ + 2 * t);
        ax += v.x; ay += v.y;
    }
    xbf[(size_t)bs * D_ + 2 * t]     = __float2bfloat16(ax);
    xbf[(size_t)bs * D_ + 2 * t + 1] = __float2bfloat16(ay);
}

// ---------------- time feature -> tf fp16 [8192][512] ----------------
__global__ void k_tf(const float* __restrict__ stime, const float* __restrict__ selw,
                     const float* __restrict__ selb, const float* __restrict__ timew,
                     const float* __restrict__ timeb, _Float16* __restrict__ tf)
{
    int bs = blockIdx.x;
    int t  = threadIdx.x;          // 128
    __shared__ float s1[64];
    float tv = stime[bs] * (1.0f / 180.0f);
    if (t < 64) {
        float u = tv * selw[t] + selb[t];
        s1[t] = 1.0f - tanhf(u * u);
    }
    __syncthreads();
    for (int d = t; d < D_; d += 128) {
        float a = timeb[d];
        const float* wr = timew + (size_t)d * 64;
        #pragma unroll 8
        for (int j = 0; j < 64; j++) a += s1[j] * wr[j];
        tf[(size_t)bs * D_ + d] = (_Float16)a;
    }
}

// ---------------- ux GEMM: [8192][512]bf16 x [2048][512]bf16^T -> [8192][2048]fp16 ----
__global__ __launch_bounds__(512) void k_gemm(const __bf16* __restrict__ A,
                                              const __bf16* __restrict__ Bm,
                                              _Float16* __restrict__ Cg)
{
    int lane = threadIdx.x & 63;
    int w    = threadIdx.x >> 6;     // 8 waves
    int wm = w & 3, wn = w >> 2;     // wave tile 32x64
    int q = lane >> 4, r = lane & 15;
    int m0 = blockIdx.y * 128 + wm * 32;
    int n0 = blockIdx.x * 128 + wn * 64;

    const __bf16* pa0 = A  + (size_t)(m0 + r) * 512 + q * 8;
    const __bf16* pa1 = pa0 + (size_t)16 * 512;
    const __bf16* pb  = Bm + (size_t)(n0 + r) * 512 + q * 8;

    f32x4 acc[2][4] = {};
    for (int k = 0; k < 512; k += 32) {
        bf16x8 a0 = *(const bf16x8*)(pa0 + k);
        bf16x8 a1 = *(const bf16x8*)(pa1 + k);
        bf16x8 b0 = *(const bf16x8*)(pb + k);
        bf16x8 b1 = *(const bf16x8*)(pb + (size_t)16 * 512 + k);
        bf16x8 b2 = *(const bf16x8*)(pb + (size_t)32 * 512 + k);
        bf16x8 b3 = *(const bf16x8*)(pb + (size_t)48 * 512 + k);
        acc[0][0] = __builtin_amdgcn_mfma_f32_16x16x32_bf16(a0, b0, acc[0][0], 0, 0, 0);
        acc[0][1] = __builtin_amdgcn_mfma_f32_16x16x32_bf16(a0, b1, acc[0][1], 0, 0, 0);
        acc[0][2] = __builtin_amdgcn_mfma_f32_16x16x32_bf16(a0, b2, acc[0][2], 0, 0, 0);
        acc[0][3] = __builtin_amdgcn_mfma_f32_16x16x32_bf16(a0, b3, acc[0][3], 0, 0, 0);
        acc[1][0] = __builtin_amdgcn_mfma_f32_16x16x32_bf16(a1, b0, acc[1][0], 0, 0, 0);
        acc[1][1] = __builtin_amdgcn_mfma_f32_16x16x32_bf16(a1, b1, acc[1][1], 0, 0, 0);
        acc[1][2] = __builtin_amdgcn_mfma_f32_16x16x32_bf16(a1, b2, acc[1][2], 0, 0, 0);
        acc[1][3] = __builtin_amdgcn_mfma_f32_16x16x32_bf16(a1, b3, acc[1][3], 0, 0, 0);
    }
    for (int am = 0; am < 2; am++)
        for (int bn = 0; bn < 4; bn++) {
            int row = m0 + am * 16 + q * 4;
            int col = n0 + bn * 16 + r;
            _Float16* cp = Cg + (size_t)row * 2048 + col;
            #pragma unroll
            for (int t = 0; t < 4; t++) cp[(size_t)t * 2048] = (_Float16)acc[am][bn][t];
        }
}

// ---------------- recurrence helpers ----------------
__device__ __forceinline__ float dp2(int h, int w, float acc)
{
#if __has_builtin(__builtin_amdgcn_fdot2)
    return __builtin_amdgcn_fdot2(__builtin_bit_cast(v2h, h),
                                  __builtin_bit_cast(v2h, w), acc, false);
#else
    v2h a = __builtin_bit_cast(v2h, h), b = __builtin_bit_cast(v2h, w);
    return acc + (float)a.x * (float)b.x + (float)a.y * (float)b.y;
#endif
}

__device__ __forceinline__ float dot8(int4 h, int4 w, float acc)
{
    acc = dp2(h.x, w.x, acc);
    acc = dp2(h.y, w.y, acc);
    acc = dp2(h.z, w.z, acc);
    acc = dp2(h.w, w.w, acc);
    return acc;
}

// ---------------- recurrence: 32 groups x 8 blocks, weights in VGPRs -------------
// Group gid = bid>>3, batches {2gid, 2gid+1}. Member m = bid&7 owns d-slice m*64.
// SELF-FLAGGING exchange: xb[s][gid][member][64] u64, each u64 =
// (pack16(h0)|pack16(c0)<<16) | (pack16(h1)|pack16(c1)<<16)<<32 for one d,
// prefilled with fp16-NaN sentinel 0x7FFF in every half-word. Pointwise lanes
// store their u64 directly (relaxed agent, fire-and-forget — data IS the flag).
// Consumer wave w polls member w's 64 u64s (one per lane) until both 32-bit
// halves are non-sentinel; 4B store atomicity makes tearing benign.
__global__ __launch_bounds__(512, 2) void k_rnn6(
    const _Float16* __restrict__ Wg, const _Float16* __restrict__ Wd,
    const float* __restrict__ cbv, const float* __restrict__ wdb,
    const _Float16* __restrict__ ux, const _Float16* __restrict__ tf,
    const float* __restrict__ outw,
    float* __restrict__ pooled_red,
    unsigned long long* __restrict__ xb64)
{
    const int t    = threadIdx.x;
    const int gid  = blockIdx.x >> 3;
    const int m    = blockIdx.x & 7;
    const int d0   = m * 64;
    const int b0   = gid * 2;
    const int rr   = t >> 3;           // 0..63 local d (weight row / pointwise d)
    const int q8   = t & 7;            // k-eighth
    const int w    = t >> 6;           // wave id = consumed member id
    const int lane = t & 63;

    // ---- weights -> VGPRs (chunk order rotated by q8: conflict-free LDS reads) ----
    int4 Wf[8], Wi[8], Wo[8], Wc[8], Wdr[8];
    {
        const int4* p0 = (const int4*)(Wg + ((size_t)(0 * 512 + d0 + rr) * 512 + q8 * 64));
        const int4* p1 = (const int4*)(Wg + ((size_t)(1 * 512 + d0 + rr) * 512 + q8 * 64));
        const int4* p2 = (const int4*)(Wg + ((size_t)(2 * 512 + d0 + rr) * 512 + q8 * 64));
        const int4* p3 = (const int4*)(Wg + ((size_t)(3 * 512 + d0 + rr) * 512 + q8 * 64));
        const int4* pd = (const int4*)(Wd + ((size_t)(d0 + rr) * 512 + q8 * 64));
        #pragma unroll
        for (int i = 0; i < 8; i++) {
            int j = (i + q8) & 7;
            Wf[i] = p0[j]; Wi[i] = p1[j]; Wo[i] = p2[j]; Wc[i] = p3[j]; Wdr[i] = pd[j];
        }
    }

    __shared__ __align__(16) unsigned short hbuf[2][512];
    __shared__ __align__(16) unsigned short cbuf[2][512];
    __shared__ float pstg[2][64];

    float c_reg[2] = {0.f, 0.f};
    float pool[2]  = {-1e30f, -1e30f};

    float cbf = 0, cbi = 0, cbo = 0, cbc = 0, bdv = 0;
    if (q8 == 0) {
        int d = d0 + rr;
        cbf = cbv[d]; cbi = cbv[512 + d]; cbo = cbv[1024 + d]; cbc = cbv[1536 + d];
        bdv = wdb[d];
    }

    const int dw = w * 64 + lane;      // staging target d for this thread

    for (int s = 0; s < S_; s++) {
        // ux/tf prefetch (independent of h; flies during the poll)
        float uf[2], ui2[2], uo[2], uc[2], tv[2];
        if (q8 == 0) {
            #pragma unroll
            for (int b = 0; b < 2; b++) {
                size_t bs = (size_t)(b0 + b) * S_ + s;
                const _Float16* up = ux + bs * 2048 + (d0 + rr);
                uf[b]  = (float)up[0];    ui2[b] = (float)up[512];
                uo[b]  = (float)up[1024]; uc[b]  = (float)up[1536];
                tv[b]  = (float)tf[bs * 512 + (d0 + rr)];
            }
        }

        // poll member w's self-flagging u64 (h0,c0,h1,c1 for d = w*64+lane)
        unsigned long long val = 0ull;
        if (s > 0) {
            const unsigned long long* src =
                xb64 + (((size_t)s * 32 + gid) * 8 + w) * 64 + lane;
            int tries = 0;
            for (;;) {
                val = __hip_atomic_load(src, __ATOMIC_RELAXED,
                                        __HIP_MEMORY_SCOPE_AGENT);
                if ((unsigned)val != SENT32 && (unsigned)(val >> 32) != SENT32)
                    break;
                if (++tries > (1 << 22)) break;   // safety valve vs dead container
            }
        }
        __syncthreads();              // B2: prior step's hbuf/cbuf readers done
        hbuf[0][dw] = (unsigned short)(val);
        cbuf[0][dw] = (unsigned short)(val >> 16);
        hbuf[1][dw] = (unsigned short)(val >> 32);
        cbuf[1][dw] = (unsigned short)(val >> 48);
        __syncthreads();              // B1: staging visible

        // dot phase: register weights x LDS h/c (rotated chunk order)
        float ag[2][4], ad[2];
        #pragma unroll
        for (int b = 0; b < 2; b++) {
            const int4* hp = (const int4*)hbuf[b] + q8 * 8;
            const int4* cp = (const int4*)cbuf[b] + q8 * 8;
            float f_ = 0, i_ = 0, o_ = 0, c_ = 0, d_ = 0;
            #pragma unroll
            for (int i = 0; i < 8; i++) {
                int j = (i + q8) & 7;
                int4 hv = hp[j];
                f_ = dot8(hv, Wf[i], f_);
                i_ = dot8(hv, Wi[i], i_);
                o_ = dot8(hv, Wo[i], o_);
                c_ = dot8(hv, Wc[i], c_);
            }
            #pragma unroll
            for (int i = 0; i < 8; i++) {
                int j = (i + q8) & 7;
                d_ = dot8(cp[j], Wdr[i], d_);
            }
            ag[b][0] = f_; ag[b][1] = i_; ag[b][2] = o_; ag[b][3] = c_; ad[b] = d_;
        }
        // reduce over the 8 k-eighth lanes (intra-wave)
        #pragma unroll
        for (int off = 1; off < 8; off <<= 1) {
            #pragma unroll
            for (int b = 0; b < 2; b++) {
                ag[b][0] += __shfl_xor(ag[b][0], off);
                ag[b][1] += __shfl_xor(ag[b][1], off);
                ag[b][2] += __shfl_xor(ag[b][2], off);
                ag[b][3] += __shfl_xor(ag[b][3], off);
                ad[b]    += __shfl_xor(ad[b],    off);
            }
        }

        // pointwise + direct self-flagging publish (no gather, no drain, no flag)
        if (q8 == 0) {
            unsigned long long ov = 0ull;
            #pragma unroll
            for (int b = 0; b < 2; b++) {
                float gf = 1.f / (1.f + expf(-(ag[b][0] + cbf + uf[b])));
                float gi = 1.f / (1.f + expf(-(ag[b][1] + cbi + ui2[b])));
                float go = 1.f / (1.f + expf(-(ag[b][2] + cbo + uo[b])));
                float gc = 1.f / (1.f + expf(-(ag[b][3] + cbc + uc[b])));
                float cs1  = tanhf(ad[b] + bdv);
                float cadj = c_reg[b] - cs1 + cs1 * tv[b];
                float cn   = gf * cadj + gi * gc;
                float hn   = go * tanhf(cn);
                c_reg[b] = cn;
                pool[b]  = fmaxf(pool[b], hn);
                unsigned hh = __builtin_bit_cast(unsigned short, (_Float16)hn);
                unsigned cc = __builtin_bit_cast(unsigned short, (_Float16)cn);
                ov |= ((unsigned long long)(hh | (cc << 16))) << (32 * b);
            }
            if (s != S_ - 1) {
                unsigned long long* dst =
                    xb64 + (((size_t)(s + 1) * 32 + gid) * 8 + m) * 64 + rr;
                __hip_atomic_store(dst, ov, __ATOMIC_RELAXED,
                                   __HIP_MEMORY_SCOPE_AGENT);
            }
        }
    }

    // pooled epilogue
    if (q8 == 0) { pstg[0][rr] = pool[0]; pstg[1][rr] = pool[1]; }
    __syncthreads();
    if (t < 128) {
        int b = t >> 6, l = t & 63;
        float pv = pstg[b][l];
        int d = d0 + l;
        float p0 = pv * outw[d], p1 = pv * outw[512 + d];
        #pragma unroll
        for (int off = 32; off > 0; off >>= 1) {
            p0 += __shfl_down(p0, off);
            p1 += __shfl_down(p1, off);
        }
        if (l == 0) {
            atomicAdd(&pooled_red[2 * (b0 + b)],     p0);
            atomicAdd(&pooled_red[2 * (b0 + b) + 1], p1);
        }
    }
}

// ---------------- final output ----------------
__global__ void k_out(const float* __restrict__ pr, const float* __restrict__ outb,
                      float* __restrict__ out)
{
    int i = threadIdx.x;
    if (i < 128) out[i] = pr[i] + outb[i & 1];
}

// ---------------- launch ----------------
extern "C" void kernel_launch(void* const* d_in, const int* in_sizes, int n_in,
                              void* d_out, int out_size, void* d_ws, size_t ws_size,
                              hipStream_t stream)
{
    const float* emb   = (const float*)d_in[0];
    const float* Wall  = (const float*)d_in[1];
    const float* Wallb = (const float*)d_in[2];
    const float* Uall  = (const float*)d_in[3];
    const float* Uallb = (const float*)d_in[4];
    const float* Wdw   = (const float*)d_in[5];
    const float* Wdb   = (const float*)d_in[6];
    const float* selw  = (const float*)d_in[7];
    const float* selb  = (const float*)d_in[8];
    const float* timew = (const float*)d_in[9];
    const float* timeb = (const float*)d_in[10];
    const float* outw  = (const float*)d_in[11];
    const float* outb  = (const float*)d_in[12];
    const float* stime = (const float*)d_in[13];
    const int*   seqs  = (const int*)d_in[14];
    float* out = (float*)d_out;
    char*  ws  = (char*)d_ws;

    __hip_bfloat16* xbf = (__hip_bfloat16*)(ws + OFF_XBF);
    __hip_bfloat16* ubf = (__hip_bfloat16*)(ws + OFF_UBF);
    _Float16* wg   = (_Float16*)(ws + OFF_WG);
    _Float16* wd   = (_Float16*)(ws + OFF_WD);
    float*    cbp  = (float*)(ws + OFF_CB);
    float*    pred = (float*)(ws + OFF_SYNC + 4096);
    _Float16* tfp  = (_Float16*)(ws + OFF_TF);
    _Float16* uxp  = (_Float16*)(ws + OFF_UX);
    unsigned long long* xb = (unsigned long long*)(ws + OFF_XB2);

    k_zero     <<<2,    256, 0, stream>>>((int4*)(ws + OFF_SYNC));
    k_fill     <<<4096, 256, 0, stream>>>((int4*)(ws + OFF_XB2));   // 16 MB sentinel
    k_prep_wall<<<4096, 256, 0, stream>>>(Wall, wg);
    k_prep_wd  <<<1024, 256, 0, stream>>>(Wdw, wd);
    k_prep_u   <<<4096, 256, 0, stream>>>(Uall, ubf);
    k_prep_cb  <<<8,    256, 0, stream>>>(Wallb, Uallb, cbp);
    k_embed    <<<B_ * S_, 256, 0, stream>>>(emb, seqs, xbf);
    k_tf       <<<B_ * S_, 128, 0, stream>>>(stime, selw, selb, timew, timeb, tfp);
    k_gemm     <<<dim3(16, 64), 512, 0, stream>>>((const __bf16*)xbf, (const __bf16*)ubf, uxp);
    k_rnn6     <<<256, 512, 0, stream>>>(wg, wd, cbp, Wdb, uxp, tfp, outw,
                                         pred, xb);
    k_out      <<<1, 128, 0, stream>>>(pred, outb, out);
}

// Round 7
// 675.459 us; speedup vs baseline: 1.7541x; 1.4721x over previous
//
#include <hip/hip_runtime.h>
#include <hip/hip_bf16.h>

// Problem constants
#define B_ 64
#define S_ 128
#define C_ 32
#define D_ 512
#define V_ 20000

typedef __bf16    bf16x8 __attribute__((ext_vector_type(8)));
typedef float     f32x4  __attribute__((ext_vector_type(4)));
typedef _Float16  f16x8  __attribute__((ext_vector_type(8)));

// ---- workspace layout (bytes) ----
#define OFF_XBF  0ull          // bf16 x   [8192][512]    8,388,608
#define OFF_UBF  8388608ull    // bf16 U   [2048][512]    2,097,152
#define OFF_AW   10485760ull   // fp16 MFMA-swizzled weights [8m][8w][3t][16kt][64l][8] = 3,145,728
#define OFF_CB   13631488ull   // f32 cb[2048]                8,192
#define OFF_SYNC 13639680ull   // pad @0 ; f32 pooled_red[128] @4096 ; 8 KB
#define OFF_TF   13647872ull   // fp16 tf [8192][512]     8,388,608
#define OFF_UX   22036480ull   // fp16 ux [8192][2048]   33,554,432
#define OFF_XB2  55590912ull   // u64 xb[128][32][8][64] = 16,777,216 (self-flagging)
                               // total 72,368,128 B

#define SENT32 0x7FFF7FFFu     // two fp16 NaNs — never produced by finite (h,c) pack

// ---------------- zero kernel (pooled_red) ----------------
__global__ void k_zero(int4* __restrict__ p)
{
    p[blockIdx.x * 256 + threadIdx.x] = int4{0, 0, 0, 0};
}

// ---------------- sentinel prefill for the exchange buffer ----------------
__global__ void k_fill(int4* __restrict__ p)
{
    p[blockIdx.x * 256 + threadIdx.x] =
        int4{(int)SENT32, (int)SENT32, (int)SENT32, (int)SENT32};
}

// ---------------- weight swizzle into MFMA A-fragment layout ----------------
// Row order per (m, wave w, tile): row16<8 -> quantity q = tile*2, else tile*2+1;
// q: 0=f,1=i,2=o,3=c,4=Wd,5=zero-pad. d = m*64 + w*8 + (row16&7).
// A-frag (16x16x32): lane = quad*16+row16 holds W[row][kt*32+quad*8 .. +8].
__global__ void k_prep_wswz(const float* __restrict__ Wall, const float* __restrict__ Wd,
                            int4* __restrict__ AW)
{
    int i = blockIdx.x * 256 + threadIdx.x;    // 0 .. 196607
    int lane = i & 63;  int r = i >> 6;
    int kt = r & 15;    r >>= 4;
    int tile = r % 3;   r /= 3;
    int w = r & 7;      int m = r >> 3;
    int row16 = lane & 15, quad = lane >> 4;
    int q = tile * 2 + (row16 >> 3);
    int d = m * 64 + w * 8 + (row16 & 7);
    int k0 = kt * 32 + quad * 8;
    union { _Float16 h[8]; int4 v; } u;
    const float* src = nullptr;
    if (q < 4)       src = Wall + (size_t)(q * 512 + d) * 512 + k0;
    else if (q == 4) src = Wd   + (size_t)d * 512 + k0;
    #pragma unroll
    for (int j = 0; j < 8; j++) u.h[j] = src ? (_Float16)src[j] : (_Float16)0.f;
    AW[i] = u.v;
}

// ---------------- prep kernels ----------------
__global__ void k_prep_u(const float* __restrict__ U, __hip_bfloat16* __restrict__ o)
{
    int i = blockIdx.x * 256 + threadIdx.x;      // 0 .. 1048575
    o[i] = __float2bfloat16(U[i]);
}

__global__ void k_prep_cb(const float* __restrict__ a, const float* __restrict__ b,
                          float* __restrict__ o)
{
    int i = blockIdx.x * 256 + threadIdx.x;      // 0 .. 2047
    o[i] = a[i] + b[i];
}

// ---------------- embedding gather-sum -> x bf16 ----------------
__global__ void k_embed(const float* __restrict__ emb, const int* __restrict__ seqs,
                        __hip_bfloat16* __restrict__ xbf)
{
    int bs = blockIdx.x;           // b*S + s
    int t  = threadIdx.x;          // 256 threads, 2 floats each
    const int* ip = seqs + (size_t)bs * C_;
    float ax = 0.f, ay = 0.f;
    for (int c = 0; c < C_; c++) {
        int row = ip[c];
        if (row < 0) row = V_;
        const float2 v = *(const float2*)(emb + (size_t)row * D_ + 2 * t);
        ax += v.x; ay += v.y;
    }
    xbf[(size_t)bs * D_ + 2 * t]     = __float2bfloat16(ax);
    xbf[(size_t)bs * D_ + 2 * t + 1] = __float2bfloat16(ay);
}

// ---------------- time feature -> tf fp16 [8192][512] ----------------
__global__ void k_tf(const float* __restrict__ stime, const float* __restrict__ selw,
                     const float* __restrict__ selb, const float* __restrict__ timew,
                     const float* __restrict__ timeb, _Float16* __restrict__ tf)
{
    int bs = blockIdx.x;
    int t  = threadIdx.x;          // 128
    __shared__ float s1[64];
    float tv = stime[bs] * (1.0f / 180.0f);
    if (t < 64) {
        float u = tv * selw[t] + selb[t];
        s1[t] = 1.0f - tanhf(u * u);
    }
    __syncthreads();
    for (int d = t; d < D_; d += 128) {
        float a = timeb[d];
        const float* wr = timew + (size_t)d * 64;
        #pragma unroll 8
        for (int j = 0; j < 64; j++) a += s1[j] * wr[j];
        tf[(size_t)bs * D_ + d] = (_Float16)a;
    }
}

// ---------------- ux GEMM: [8192][512]bf16 x [2048][512]bf16^T -> [8192][2048]fp16 ----
__global__ __launch_bounds__(512) void k_gemm(const __bf16* __restrict__ A,
                                              const __bf16* __restrict__ Bm,
                                              _Float16* __restrict__ Cg)
{
    int lane = threadIdx.x & 63;
    int w    = threadIdx.x >> 6;     // 8 waves
    int wm = w & 3, wn = w >> 2;     // wave tile 32x64
    int q = lane >> 4, r = lane & 15;
    int m0 = blockIdx.y * 128 + wm * 32;
    int n0 = blockIdx.x * 128 + wn * 64;

    const __bf16* pa0 = A  + (size_t)(m0 + r) * 512 + q * 8;
    const __bf16* pa1 = pa0 + (size_t)16 * 512;
    const __bf16* pb  = Bm + (size_t)(n0 + r) * 512 + q * 8;

    f32x4 acc[2][4] = {};
    for (int k = 0; k < 512; k += 32) {
        bf16x8 a0 = *(const bf16x8*)(pa0 + k);
        bf16x8 a1 = *(const bf16x8*)(pa1 + k);
        bf16x8 b0 = *(const bf16x8*)(pb + k);
        bf16x8 b1 = *(const bf16x8*)(pb + (size_t)16 * 512 + k);
        bf16x8 b2 = *(const bf16x8*)(pb + (size_t)32 * 512 + k);
        bf16x8 b3 = *(const bf16x8*)(pb + (size_t)48 * 512 + k);
        acc[0][0] = __builtin_amdgcn_mfma_f32_16x16x32_bf16(a0, b0, acc[0][0], 0, 0, 0);
        acc[0][1] = __builtin_amdgcn_mfma_f32_16x16x32_bf16(a0, b1, acc[0][1], 0, 0, 0);
        acc[0][2] = __builtin_amdgcn_mfma_f32_16x16x32_bf16(a0, b2, acc[0][2], 0, 0, 0);
        acc[0][3] = __builtin_amdgcn_mfma_f32_16x16x32_bf16(a0, b3, acc[0][3], 0, 0, 0);
        acc[1][0] = __builtin_amdgcn_mfma_f32_16x16x32_bf16(a1, b0, acc[1][0], 0, 0, 0);
        acc[1][1] = __builtin_amdgcn_mfma_f32_16x16x32_bf16(a1, b1, acc[1][1], 0, 0, 0);
        acc[1][2] = __builtin_amdgcn_mfma_f32_16x16x32_bf16(a1, b2, acc[1][2], 0, 0, 0);
        acc[1][3] = __builtin_amdgcn_mfma_f32_16x16x32_bf16(a1, b3, acc[1][3], 0, 0, 0);
    }
    for (int am = 0; am < 2; am++)
        for (int bn = 0; bn < 4; bn++) {
            int row = m0 + am * 16 + q * 4;
            int col = n0 + bn * 16 + r;
            _Float16* cp = Cg + (size_t)row * 2048 + col;
            #pragma unroll
            for (int t = 0; t < 4; t++) cp[(size_t)t * 2048] = (_Float16)acc[am][bn][t];
        }
}

// ---------------- fast transcendentals (v_exp + v_rcp) ----------------
__device__ __forceinline__ float fsigm(float x)
{
    return __builtin_amdgcn_rcpf(1.f + __expf(-x));
}
__device__ __forceinline__ float ftanh(float x)
{
    return 1.f - 2.f * __builtin_amdgcn_rcpf(1.f + __expf(2.f * x));
}

// ---------------- recurrence: MFMA GEMV, weights in A-frag VGPRs -------------
// 32 groups x 8 blocks; member m owns d-slice m*64. Wave w owns d-octet w*8 and
// computes its 6 quantities (f,i,o,c,wd,pad) x 16 k-tiles as 48 MFMAs; B operand
// cols: 0=h_b0,1=h_b1,2=c_b0,3=c_b1 (cols 4-15 zero). Exchange = round-6
// self-flagging per-step xb (u64 = h0|c0<<16|h1<<32|c1<<48 per d).
__global__ __launch_bounds__(512, 2) void k_rnn7(
    const int4* __restrict__ AW,
    const float* __restrict__ cbv, const float* __restrict__ wdb,
    const _Float16* __restrict__ ux, const _Float16* __restrict__ tf,
    const float* __restrict__ outw,
    float* __restrict__ pooled_red,
    unsigned long long* __restrict__ xb64)
{
    const int t    = threadIdx.x;
    const int gid  = blockIdx.x >> 3;
    const int m    = blockIdx.x & 7;
    const int b0   = gid * 2;
    const int w    = t >> 6;           // wave id: consumer of member w, owner of d-octet w*8
    const int lane = t & 63;
    const int col  = lane & 15;
    const int quad = lane >> 4;

    // ---- A-fragments -> VGPRs (48 int4 = 192 VGPR) ----
    int4 Af[48];
    {
        const int4* src = AW + (size_t)(m * 8 + w) * 3072;
        #pragma unroll
        for (int i = 0; i < 48; i++) Af[i] = src[i * 64 + lane];
    }

    __shared__ __align__(16) _Float16 xstg[4 * 544];   // 4 streams, 64B inter-pad
    __shared__ __align__(16) float cmat[8][4][48];
    __shared__ float pstg[2][64];

    const bool act = (lane < 16);      // pointwise role: b = lane>>3, j = lane&7
    const int  pb  = lane >> 3;
    const int  pj  = lane & 7;
    const int  dl  = w * 8 + pj;       // local d
    const int  d   = m * 64 + dl;      // global d

    float cbf = 0, cbi = 0, cbo = 0, cbc = 0, bdv = 0;
    if (act) {
        cbf = cbv[d]; cbi = cbv[512 + d]; cbo = cbv[1024 + d]; cbc = cbv[1536 + d];
        bdv = wdb[d];
    }
    float c_reg = 0.f, pool = -1e30f;
    const int dw = w * 64 + lane;      // staging d (consumer role)

    for (int s = 0; s < S_; s++) {
        // ux/tf prefetch (flies during the poll)
        float uf = 0, ui = 0, uo = 0, uc = 0, tv = 0;
        if (act) {
            size_t bs = (size_t)(b0 + pb) * S_ + s;
            const _Float16* up = ux + bs * 2048 + d;
            uf = (float)up[0];    ui = (float)up[512];
            uo = (float)up[1024]; uc = (float)up[1536];
            tv = (float)tf[bs * 512 + d];
        }

        // poll member w's self-flagging u64
        unsigned long long val = 0ull;
        if (s > 0) {
            const unsigned long long* src =
                xb64 + (((size_t)s * 32 + gid) * 8 + w) * 64 + lane;
            int tries = 0;
            for (;;) {
                val = __hip_atomic_load(src, __ATOMIC_RELAXED,
                                        __HIP_MEMORY_SCOPE_AGENT);
                if ((unsigned)val != SENT32 && (unsigned)(val >> 32) != SENT32)
                    break;
                if (++tries > (1 << 22)) break;   // safety valve
            }
        }
        __syncthreads();              // B2: prior step's xstg readers done
        xstg[0 * 544 + dw] = __builtin_bit_cast(_Float16, (unsigned short)(val));
        xstg[2 * 544 + dw] = __builtin_bit_cast(_Float16, (unsigned short)(val >> 16));
        xstg[1 * 544 + dw] = __builtin_bit_cast(_Float16, (unsigned short)(val >> 32));
        xstg[3 * 544 + dw] = __builtin_bit_cast(_Float16, (unsigned short)(val >> 48));
        __syncthreads();              // B1: staging visible

        // MFMA dot: 3 row-tiles x 16 k-tiles
        f32x4 a0 = {0, 0, 0, 0}, a1 = {0, 0, 0, 0}, a2 = {0, 0, 0, 0};
        #pragma unroll
        for (int kt = 0; kt < 16; kt++) {
            f16x8 b = {};
            if (col < 4)
                b = *(const f16x8*)(xstg + col * 544 + kt * 32 + quad * 8);
            a0 = __builtin_amdgcn_mfma_f32_16x16x32_f16(
                     __builtin_bit_cast(f16x8, Af[kt]),      b, a0, 0, 0, 0);
            a1 = __builtin_amdgcn_mfma_f32_16x16x32_f16(
                     __builtin_bit_cast(f16x8, Af[16 + kt]), b, a1, 0, 0, 0);
            a2 = __builtin_amdgcn_mfma_f32_16x16x32_f16(
                     __builtin_bit_cast(f16x8, Af[32 + kt]), b, a2, 0, 0, 0);
        }

        // C -> per-wave LDS (row = quad*4+reg, col = lane&15; only cols 0-3 real)
        if (col < 4) {
            *(f32x4*)&cmat[w][col][ 0 + quad * 4] = a0;
            *(f32x4*)&cmat[w][col][16 + quad * 4] = a1;
            *(f32x4*)&cmat[w][col][32 + quad * 4] = a2;
        }

        // pointwise on 16 lanes (within-wave LDS readback; no barrier needed)
        if (act) {
            float f_  = cmat[w][pb][ 0 + pj];
            float i_  = cmat[w][pb][ 8 + pj];
            float o_  = cmat[w][pb][16 + pj];
            float g_  = cmat[w][pb][24 + pj];
            float wd_ = cmat[w][2 + pb][32 + pj];
            float gf = fsigm(f_ + cbf + uf);
            float gi = fsigm(i_ + cbi + ui);
            float go = fsigm(o_ + cbo + uo);
            float gc = fsigm(g_ + cbc + uc);
            float cs1  = ftanh(wd_ + bdv);
            float cadj = c_reg - cs1 + cs1 * tv;
            float cn   = gf * cadj + gi * gc;
            float hn   = go * ftanh(cn);
            c_reg = cn;
            pool  = fmaxf(pool, hn);
            unsigned hh = __builtin_bit_cast(unsigned short, (_Float16)hn);
            unsigned cc = __builtin_bit_cast(unsigned short, (_Float16)cn);
            unsigned pk = hh | (cc << 16);
            unsigned other = __shfl(pk, lane + 8);   // lanes 0-7 fetch batch-1 pack
            if (pb == 0 && s != S_ - 1) {
                unsigned long long ov =
                    (unsigned long long)pk | ((unsigned long long)other << 32);
                unsigned long long* dst =
                    xb64 + (((size_t)(s + 1) * 32 + gid) * 8 + m) * 64 + dl;
                __hip_atomic_store(dst, ov, __ATOMIC_RELAXED,
                                   __HIP_MEMORY_SCOPE_AGENT);
            }
        }
    }

    // pooled epilogue
    if (act) pstg[pb][dl] = pool;
    __syncthreads();
    if (t < 128) {
        int b = t >> 6, l = t & 63;
        float pv = pstg[b][l];
        int dg = m * 64 + l;
        float p0 = pv * outw[dg], p1 = pv * outw[512 + dg];
        #pragma unroll
        for (int off = 32; off > 0; off >>= 1) {
            p0 += __shfl_down(p0, off);
            p1 += __shfl_down(p1, off);
        }
        if (l == 0) {
            atomicAdd(&pooled_red[2 * (b0 + b)],     p0);
            atomicAdd(&pooled_red[2 * (b0 + b) + 1], p1);
        }
    }
}

// ---------------- final output ----------------
__global__ void k_out(const float* __restrict__ pr, const float* __restrict__ outb,
                      float* __restrict__ out)
{
    int i = threadIdx.x;
    if (i < 128) out[i] = pr[i] + outb[i & 1];
}

// ---------------- launch ----------------
extern "C" void kernel_launch(void* const* d_in, const int* in_sizes, int n_in,
                              void* d_out, int out_size, void* d_ws, size_t ws_size,
                              hipStream_t stream)
{
    const float* emb   = (const float*)d_in[0];
    const float* Wall  = (const float*)d_in[1];
    const float* Wallb = (const float*)d_in[2];
    const float* Uall  = (const float*)d_in[3];
    const float* Uallb = (const float*)d_in[4];
    const float* Wdw   = (const float*)d_in[5];
    const float* Wdb   = (const float*)d_in[6];
    const float* selw  = (const float*)d_in[7];
    const float* selb  = (const float*)d_in[8];
    const float* timew = (const float*)d_in[9];
    const float* timeb = (const float*)d_in[10];
    const float* outw  = (const float*)d_in[11];
    const float* outb  = (const float*)d_in[12];
    const float* stime = (const float*)d_in[13];
    const int*   seqs  = (const int*)d_in[14];
    float* out = (float*)d_out;
    char*  ws  = (char*)d_ws;

    __hip_bfloat16* xbf = (__hip_bfloat16*)(ws + OFF_XBF);
    __hip_bfloat16* ubf = (__hip_bfloat16*)(ws + OFF_UBF);
    int4*     aw   = (int4*)(ws + OFF_AW);
    float*    cbp  = (float*)(ws + OFF_CB);
    float*    pred = (float*)(ws + OFF_SYNC + 4096);
    _Float16* tfp  = (_Float16*)(ws + OFF_TF);
    _Float16* uxp  = (_Float16*)(ws + OFF_UX);
    unsigned long long* xb = (unsigned long long*)(ws + OFF_XB2);

    k_zero     <<<2,    256, 0, stream>>>((int4*)(ws + OFF_SYNC));
    k_fill     <<<4096, 256, 0, stream>>>((int4*)(ws + OFF_XB2));   // 16 MB sentinel
    k_prep_wswz<<<768,  256, 0, stream>>>(Wall, Wdw, aw);
    k_prep_u   <<<4096, 256, 0, stream>>>(Uall, ubf);
    k_prep_cb  <<<8,    256, 0, stream>>>(Wallb, Uallb, cbp);
    k_embed    <<<B_ * S_, 256, 0, stream>>>(emb, seqs, xbf);
    k_tf       <<<B_ * S_, 128, 0, stream>>>(stime, selw, selb, timew, timeb, tfp);
    k_gemm     <<<dim3(16, 64), 512, 0, stream>>>((const __bf16*)xbf, (const __bf16*)ubf, uxp);
    k_rnn7     <<<256, 512, 0, stream>>>(aw, cbp, Wdb, uxp, tfp, outw, pred, xb);
    k_out      <<<1, 128, 0, stream>>>(pred, outb, out);
}

// Round 8
// 554.090 us; speedup vs baseline: 2.1383x; 1.2190x over previous
//
#include <hip/hip_runtime.h>
#include <hip/hip_bf16.h>

// Problem constants
#define B_ 64
#define S_ 128
#define C_ 32
#define D_ 512
#define V_ 20000

typedef float     f32x4  __attribute__((ext_vector_type(4)));
typedef _Float16  f16x8  __attribute__((ext_vector_type(8)));

// ---- workspace layout (bytes) ----
#define OFF_XH   0ull          // fp16 x   [8192][512]    8,388,608
#define OFF_UH   8388608ull    // fp16 U   [2048][512]    2,097,152
#define OFF_AW   10485760ull   // fp16 MFMA-swizzled weights = 3,145,728
#define OFF_CB   13631488ull   // f32 cb[2048]                8,192
#define OFF_SYNC 13639680ull   // pad @0 ; f32 pooled_red[128] @4096 ; 8 KB
#define OFF_TWT  13647872ull   // f32 timew^T [64][512]     131,072
#define OFF_EMBH 13778944ull   // fp16 emb [20001][512]  20,481,024
#define OFF_TF   34259968ull   // fp16 tf [8192][512]     8,388,608
#define OFF_UX   42648576ull   // fp16 ux [8192][2048]   33,554,432
#define OFF_XB2  76203008ull   // u64 xb[128][32][8][64] = 16,777,216 (self-flagging)
                               // total 92,980,224 B (round-1 layout used 97 MB -> fits)

#define SENT32 0x7FFF7FFFu     // two fp16 NaNs — never produced by finite (h,c) pack

// ---------------- zero kernel (pooled_red) ----------------
__global__ void k_zero(int4* __restrict__ p)
{
    p[blockIdx.x * 256 + threadIdx.x] = int4{0, 0, 0, 0};
}

// ---------------- sentinel prefill for the exchange buffer ----------------
__global__ void k_fill(int4* __restrict__ p)
{
    p[blockIdx.x * 256 + threadIdx.x] =
        int4{(int)SENT32, (int)SENT32, (int)SENT32, (int)SENT32};
}

// ---------------- weight swizzle into MFMA A-fragment layout ----------------
// q: 0=f,1=i,2=o,3=c,4=Wd,5=zero-pad. d = m*64 + w*8 + (row16&7).
__global__ void k_prep_wswz(const float* __restrict__ Wall, const float* __restrict__ Wd,
                            int4* __restrict__ AW)
{
    int i = blockIdx.x * 256 + threadIdx.x;    // 0 .. 196607
    int lane = i & 63;  int r = i >> 6;
    int kt = r & 15;    r >>= 4;
    int tile = r % 3;   r /= 3;
    int w = r & 7;      int m = r >> 3;
    int row16 = lane & 15, quad = lane >> 4;
    int q = tile * 2 + (row16 >> 3);
    int d = m * 64 + w * 8 + (row16 & 7);
    int k0 = kt * 32 + quad * 8;
    union { _Float16 h[8]; int4 v; } u;
    const float* src = nullptr;
    if (q < 4)       src = Wall + (size_t)(q * 512 + d) * 512 + k0;
    else if (q == 4) src = Wd   + (size_t)d * 512 + k0;
    #pragma unroll
    for (int j = 0; j < 8; j++) u.h[j] = src ? (_Float16)src[j] : (_Float16)0.f;
    AW[i] = u.v;
}

// ---------------- prep kernels ----------------
__global__ void k_prep_u(const float* __restrict__ U, _Float16* __restrict__ o)
{
    int i = blockIdx.x * 256 + threadIdx.x;      // 0 .. 1048575
    o[i] = (_Float16)U[i];
}

__global__ void k_prep_cb(const float* __restrict__ a, const float* __restrict__ b,
                          float* __restrict__ o)
{
    int i = blockIdx.x * 256 + threadIdx.x;      // 0 .. 2047
    o[i] = a[i] + b[i];
}

// emb fp32 -> fp16 (two elements per thread; grid 20001 x 256 covers 20001*512)
__global__ void k_prep_emb(const float* __restrict__ e, _Float16* __restrict__ o)
{
    int i = blockIdx.x * 256 + threadIdx.x;      // pair index
    float2 v = ((const float2*)e)[i];
    unsigned short hx = __builtin_bit_cast(unsigned short, (_Float16)v.x);
    unsigned short hy = __builtin_bit_cast(unsigned short, (_Float16)v.y);
    ((unsigned*)o)[i] = (unsigned)hx | ((unsigned)hy << 16);
}

// timew [512][64] -> timew^T [64][512]
__global__ void k_prep_twt(const float* __restrict__ tw, float* __restrict__ o)
{
    int i = blockIdx.x * 256 + threadIdx.x;      // 0 .. 32767
    int d = i >> 6, j = i & 63;
    o[j * 512 + d] = tw[i];
}

// ---------------- embedding gather-sum (fp16 table) -> x fp16 ----------------
__global__ void k_embed2(const _Float16* __restrict__ embh, const int* __restrict__ seqs,
                         _Float16* __restrict__ xh)
{
    int bs = blockIdx.x;           // b*S + s
    int t  = threadIdx.x;          // 256 threads, 2 halves each
    __shared__ int rows[32];
    if (t < 32) {
        int r = seqs[(size_t)bs * C_ + t];
        rows[t] = (r < 0) ? V_ : r;
    }
    __syncthreads();
    float ax = 0.f, ay = 0.f;
    #pragma unroll 4
    for (int c = 0; c < C_; c++) {
        unsigned v = *(const unsigned*)(embh + (size_t)rows[c] * D_ + 2 * t);
        ax += (float)__builtin_bit_cast(_Float16, (unsigned short)v);
        ay += (float)__builtin_bit_cast(_Float16, (unsigned short)(v >> 16));
    }
    unsigned short hx = __builtin_bit_cast(unsigned short, (_Float16)ax);
    unsigned short hy = __builtin_bit_cast(unsigned short, (_Float16)ay);
    *(unsigned*)(xh + (size_t)bs * D_ + 2 * t) = (unsigned)hx | ((unsigned)hy << 16);
}

// ---------------- time feature: 16 bs per block, thread-per-d ----------------
__global__ __launch_bounds__(512) void k_tf2(
    const float* __restrict__ stime, const float* __restrict__ selw,
    const float* __restrict__ selb, const float* __restrict__ twT,
    const float* __restrict__ timeb, _Float16* __restrict__ tf)
{
    int bb = blockIdx.x;           // covers bs = bb*16 .. bb*16+15
    int t  = threadIdx.x;          // 512
    __shared__ float s1[16][64];
    for (int idx = t; idx < 1024; idx += 512) {
        int bl = idx >> 6, j = idx & 63;
        float tv = stime[bb * 16 + bl] * (1.0f / 180.0f);
        float u  = tv * selw[j] + selb[j];
        s1[bl][j] = 1.0f - tanhf(u * u);
    }
    __syncthreads();
    int d = t;
    float acc[16];
    float tb = timeb[d];
    #pragma unroll
    for (int l = 0; l < 16; l++) acc[l] = tb;
    for (int j = 0; j < 64; j++) {
        float wj = twT[j * 512 + d];
        #pragma unroll
        for (int l = 0; l < 16; l++) acc[l] = fmaf(s1[l][j], wj, acc[l]);
    }
    #pragma unroll
    for (int l = 0; l < 16; l++)
        tf[(size_t)(bb * 16 + l) * 512 + d] = (_Float16)acc[l];
}

// ---------------- ux GEMM: fp16 x fp16^T -> fp16 ----------------
__global__ __launch_bounds__(512) void k_gemm(const _Float16* __restrict__ A,
                                              const _Float16* __restrict__ Bm,
                                              _Float16* __restrict__ Cg)
{
    int lane = threadIdx.x & 63;
    int w    = threadIdx.x >> 6;     // 8 waves
    int wm = w & 3, wn = w >> 2;     // wave tile 32x64
    int q = lane >> 4, r = lane & 15;
    int m0 = blockIdx.y * 128 + wm * 32;
    int n0 = blockIdx.x * 128 + wn * 64;

    const _Float16* pa0 = A  + (size_t)(m0 + r) * 512 + q * 8;
    const _Float16* pa1 = pa0 + (size_t)16 * 512;
    const _Float16* pb  = Bm + (size_t)(n0 + r) * 512 + q * 8;

    f32x4 acc[2][4] = {};
    for (int k = 0; k < 512; k += 32) {
        f16x8 a0 = *(const f16x8*)(pa0 + k);
        f16x8 a1 = *(const f16x8*)(pa1 + k);
        f16x8 b0 = *(const f16x8*)(pb + k);
        f16x8 b1 = *(const f16x8*)(pb + (size_t)16 * 512 + k);
        f16x8 b2 = *(const f16x8*)(pb + (size_t)32 * 512 + k);
        f16x8 b3 = *(const f16x8*)(pb + (size_t)48 * 512 + k);
        acc[0][0] = __builtin_amdgcn_mfma_f32_16x16x32_f16(a0, b0, acc[0][0], 0, 0, 0);
        acc[0][1] = __builtin_amdgcn_mfma_f32_16x16x32_f16(a0, b1, acc[0][1], 0, 0, 0);
        acc[0][2] = __builtin_amdgcn_mfma_f32_16x16x32_f16(a0, b2, acc[0][2], 0, 0, 0);
        acc[0][3] = __builtin_amdgcn_mfma_f32_16x16x32_f16(a0, b3, acc[0][3], 0, 0, 0);
        acc[1][0] = __builtin_amdgcn_mfma_f32_16x16x32_f16(a1, b0, acc[1][0], 0, 0, 0);
        acc[1][1] = __builtin_amdgcn_mfma_f32_16x16x32_f16(a1, b1, acc[1][1], 0, 0, 0);
        acc[1][2] = __builtin_amdgcn_mfma_f32_16x16x32_f16(a1, b2, acc[1][2], 0, 0, 0);
        acc[1][3] = __builtin_amdgcn_mfma_f32_16x16x32_f16(a1, b3, acc[1][3], 0, 0, 0);
    }
    for (int am = 0; am < 2; am++)
        for (int bn = 0; bn < 4; bn++) {
            int row = m0 + am * 16 + q * 4;
            int col = n0 + bn * 16 + r;
            _Float16* cp = Cg + (size_t)row * 2048 + col;
            #pragma unroll
            for (int t = 0; t < 4; t++) cp[(size_t)t * 2048] = (_Float16)acc[am][bn][t];
        }
}

// ---------------- fast transcendentals (v_exp + v_rcp) ----------------
__device__ __forceinline__ float fsigm(float x)
{
    return __builtin_amdgcn_rcpf(1.f + __expf(-x));
}
__device__ __forceinline__ float ftanh(float x)
{
    return 1.f - 2.f * __builtin_amdgcn_rcpf(1.f + __expf(2.f * x));
}

// ---------------- recurrence: MFMA GEMV, weights in A-frag VGPRs -------------
// (unchanged from round 7 — proven at 293 us)
__global__ __launch_bounds__(512, 2) void k_rnn7(
    const int4* __restrict__ AW,
    const float* __restrict__ cbv, const float* __restrict__ wdb,
    const _Float16* __restrict__ ux, const _Float16* __restrict__ tf,
    const float* __restrict__ outw,
    float* __restrict__ pooled_red,
    unsigned long long* __restrict__ xb64)
{
    const int t    = threadIdx.x;
    const int gid  = blockIdx.x >> 3;
    const int m    = blockIdx.x & 7;
    const int b0   = gid * 2;
    const int w    = t >> 6;           // wave id: consumer of member w, owner of d-octet w*8
    const int lane = t & 63;
    const int col  = lane & 15;
    const int quad = lane >> 4;

    int4 Af[48];
    {
        const int4* src = AW + (size_t)(m * 8 + w) * 3072;
        #pragma unroll
        for (int i = 0; i < 48; i++) Af[i] = src[i * 64 + lane];
    }

    __shared__ __align__(16) _Float16 xstg[4 * 544];   // 4 streams, 64B inter-pad
    __shared__ __align__(16) float cmat[8][4][48];
    __shared__ float pstg[2][64];

    const bool act = (lane < 16);
    const int  pb  = lane >> 3;
    const int  pj  = lane & 7;
    const int  dl  = w * 8 + pj;
    const int  d   = m * 64 + dl;

    float cbf = 0, cbi = 0, cbo = 0, cbc = 0, bdv = 0;
    if (act) {
        cbf = cbv[d]; cbi = cbv[512 + d]; cbo = cbv[1024 + d]; cbc = cbv[1536 + d];
        bdv = wdb[d];
    }
    float c_reg = 0.f, pool = -1e30f;
    const int dw = w * 64 + lane;

    for (int s = 0; s < S_; s++) {
        float uf = 0, ui = 0, uo = 0, uc = 0, tv = 0;
        if (act) {
            size_t bs = (size_t)(b0 + pb) * S_ + s;
            const _Float16* up = ux + bs * 2048 + d;
            uf = (float)up[0];    ui = (float)up[512];
            uo = (float)up[1024]; uc = (float)up[1536];
            tv = (float)tf[bs * 512 + d];
        }

        unsigned long long val = 0ull;
        if (s > 0) {
            const unsigned long long* src =
                xb64 + (((size_t)s * 32 + gid) * 8 + w) * 64 + lane;
            int tries = 0;
            for (;;) {
                val = __hip_atomic_load(src, __ATOMIC_RELAXED,
                                        __HIP_MEMORY_SCOPE_AGENT);
                if ((unsigned)val != SENT32 && (unsigned)(val >> 32) != SENT32)
                    break;
                if (++tries > (1 << 22)) break;   // safety valve
            }
        }
        __syncthreads();              // B2: prior step's xstg readers done
        xstg[0 * 544 + dw] = __builtin_bit_cast(_Float16, (unsigned short)(val));
        xstg[2 * 544 + dw] = __builtin_bit_cast(_Float16, (unsigned short)(val >> 16));
        xstg[1 * 544 + dw] = __builtin_bit_cast(_Float16, (unsigned short)(val >> 32));
        xstg[3 * 544 + dw] = __builtin_bit_cast(_Float16, (unsigned short)(val >> 48));
        __syncthreads();              // B1: staging visible

        f32x4 a0 = {0, 0, 0, 0}, a1 = {0, 0, 0, 0}, a2 = {0, 0, 0, 0};
        #pragma unroll
        for (int kt = 0; kt < 16; kt++) {
            f16x8 b = {};
            if (col < 4)
                b = *(const f16x8*)(xstg + col * 544 + kt * 32 + quad * 8);
            a0 = __builtin_amdgcn_mfma_f32_16x16x32_f16(
                     __builtin_bit_cast(f16x8, Af[kt]),      b, a0, 0, 0, 0);
            a1 = __builtin_amdgcn_mfma_f32_16x16x32_f16(
                     __builtin_bit_cast(f16x8, Af[16 + kt]), b, a1, 0, 0, 0);
            a2 = __builtin_amdgcn_mfma_f32_16x16x32_f16(
                     __builtin_bit_cast(f16x8, Af[32 + kt]), b, a2, 0, 0, 0);
        }

        if (col < 4) {
            *(f32x4*)&cmat[w][col][ 0 + quad * 4] = a0;
            *(f32x4*)&cmat[w][col][16 + quad * 4] = a1;
            *(f32x4*)&cmat[w][col][32 + quad * 4] = a2;
        }

        if (act) {
            float f_  = cmat[w][pb][ 0 + pj];
            float i_  = cmat[w][pb][ 8 + pj];
            float o_  = cmat[w][pb][16 + pj];
            float g_  = cmat[w][pb][24 + pj];
            float wd_ = cmat[w][2 + pb][32 + pj];
            float gf = fsigm(f_ + cbf + uf);
            float gi = fsigm(i_ + cbi + ui);
            float go = fsigm(o_ + cbo + uo);
            float gc = fsigm(g_ + cbc + uc);
            float cs1  = ftanh(wd_ + bdv);
            float cadj = c_reg - cs1 + cs1 * tv;
            float cn   = gf * cadj + gi * gc;
            float hn   = go * ftanh(cn);
            c_reg = cn;
            pool  = fmaxf(pool, hn);
            unsigned hh = __builtin_bit_cast(unsigned short, (_Float16)hn);
            unsigned cc = __builtin_bit_cast(unsigned short, (_Float16)cn);
            unsigned pk = hh | (cc << 16);
            unsigned other = __shfl(pk, lane + 8);
            if (pb == 0 && s != S_ - 1) {
                unsigned long long ov =
                    (unsigned long long)pk | ((unsigned long long)other << 32);
                unsigned long long* dst =
                    xb64 + (((size_t)(s + 1) * 32 + gid) * 8 + m) * 64 + dl;
                __hip_atomic_store(dst, ov, __ATOMIC_RELAXED,
                                   __HIP_MEMORY_SCOPE_AGENT);
            }
        }
    }

    // pooled epilogue
    if (act) pstg[pb][dl] = pool;
    __syncthreads();
    if (t < 128) {
        int b = t >> 6, l = t & 63;
        float pv = pstg[b][l];
        int dg = m * 64 + l;
        float p0 = pv * outw[dg], p1 = pv * outw[512 + dg];
        #pragma unroll
        for (int off = 32; off > 0; off >>= 1) {
            p0 += __shfl_down(p0, off);
            p1 += __shfl_down(p1, off);
        }
        if (l == 0) {
            atomicAdd(&pooled_red[2 * (b0 + b)],     p0);
            atomicAdd(&pooled_red[2 * (b0 + b) + 1], p1);
        }
    }
}

// ---------------- final output ----------------
__global__ void k_out(const float* __restrict__ pr, const float* __restrict__ outb,
                      float* __restrict__ out)
{
    int i = threadIdx.x;
    if (i < 128) out[i] = pr[i] + outb[i & 1];
}

// ---------------- launch ----------------
extern "C" void kernel_launch(void* const* d_in, const int* in_sizes, int n_in,
                              void* d_out, int out_size, void* d_ws, size_t ws_size,
                              hipStream_t stream)
{
    const float* emb   = (const float*)d_in[0];
    const float* Wall  = (const float*)d_in[1];
    const float* Wallb = (const float*)d_in[2];
    const float* Uall  = (const float*)d_in[3];
    const float* Uallb = (const float*)d_in[4];
    const float* Wdw   = (const float*)d_in[5];
    const float* Wdb   = (const float*)d_in[6];
    const float* selw  = (const float*)d_in[7];
    const float* selb  = (const float*)d_in[8];
    const float* timew = (const float*)d_in[9];
    const float* timeb = (const float*)d_in[10];
    const float* outw  = (const float*)d_in[11];
    const float* outb  = (const float*)d_in[12];
    const float* stime = (const float*)d_in[13];
    const int*   seqs  = (const int*)d_in[14];
    float* out = (float*)d_out;
    char*  ws  = (char*)d_ws;

    _Float16* xh   = (_Float16*)(ws + OFF_XH);
    _Float16* uh   = (_Float16*)(ws + OFF_UH);
    int4*     aw   = (int4*)(ws + OFF_AW);
    float*    cbp  = (float*)(ws + OFF_CB);
    float*    pred = (float*)(ws + OFF_SYNC + 4096);
    float*    twt  = (float*)(ws + OFF_TWT);
    _Float16* eh   = (_Float16*)(ws + OFF_EMBH);
    _Float16* tfp  = (_Float16*)(ws + OFF_TF);
    _Float16* uxp  = (_Float16*)(ws + OFF_UX);
    unsigned long long* xb = (unsigned long long*)(ws + OFF_XB2);

    k_zero     <<<2,     256, 0, stream>>>((int4*)(ws + OFF_SYNC));
    k_fill     <<<4096,  256, 0, stream>>>((int4*)(ws + OFF_XB2));   // 16 MB sentinel
    k_prep_emb <<<20001, 256, 0, stream>>>(emb, eh);
    k_prep_wswz<<<768,   256, 0, stream>>>(Wall, Wdw, aw);
    k_prep_u   <<<4096,  256, 0, stream>>>(Uall, uh);
    k_prep_cb  <<<8,     256, 0, stream>>>(Wallb, Uallb, cbp);
    k_prep_twt <<<128,   256, 0, stream>>>(timew, twt);
    k_embed2   <<<B_ * S_, 256, 0, stream>>>(eh, seqs, xh);
    k_tf2      <<<512,   512, 0, stream>>>(stime, selw, selb, twt, timeb, tfp);
    k_gemm     <<<dim3(16, 64), 512, 0, stream>>>(xh, uh, uxp);
    k_rnn7     <<<256,   512, 0, stream>>>(aw, cbp, Wdb, uxp, tfp, outw, pred, xb);
    k_out      <<<1,     128, 0, stream>>>(pred, outb, out);
}

// Round 9
// 471.080 us; speedup vs baseline: 2.5151x; 1.1762x over previous
//
#include <hip/hip_runtime.h>
#include <hip/hip_bf16.h>

// Problem constants
#define B_ 64
#define S_ 128
#define C_ 32
#define D_ 512
#define V_ 20000

typedef float     f32x4  __attribute__((ext_vector_type(4)));
typedef _Float16  f16x8  __attribute__((ext_vector_type(8)));

#define AS1 __attribute__((address_space(1)))
#define AS3 __attribute__((address_space(3)))

// ---- workspace layout (bytes) ----
#define OFF_XH   0ull          // fp16 x   [8192][512]    8,388,608
#define OFF_UH   8388608ull    // fp16 U   [2048][512]    2,097,152
#define OFF_AW   10485760ull   // fp16 MFMA-swizzled weights = 3,145,728
#define OFF_CB   13631488ull   // f32 cb[2048]                8,192
#define OFF_PAD  13639680ull   // 8 KB pad (unused)
#define OFF_TWT  13647872ull   // f32 timew^T [64][512]     131,072
#define OFF_EMBH 13778944ull   // fp16 emb [20001][512]  20,481,024
#define OFF_TF   34259968ull   // fp16 tf [8192][512]     8,388,608
#define OFF_UX   42648576ull   // fp16 ux [8192][2048]   33,554,432
#define OFF_XB2  76203008ull   // u64 xb[128][32][8][64] = 16,777,216 (self-flagging)
                               // total 92,980,224 B

#define SENT32 0x7FFF7FFFu     // two fp16 NaNs — never produced by finite (h,c) pack

// ---------------- fused prep kernel (segmented by blockIdx) ----------------
// SEG0 [0,1): d_out init with bias
// SEG1 [1,4097): sentinel fill 16 MB
// SEG2 [4097,4098): cb = Wallb + Uallb
// SEG3 [4098,4130): timew^T
// SEG4 [4130,5154): U fp32->fp16
// SEG5 [5154,5922): W_all/W_d -> MFMA A-frag swizzle
// SEG6 [5922,25923): emb fp32->fp16
__global__ void k_prep_fused(
    const float* __restrict__ outb, float* __restrict__ outv,
    int4* __restrict__ fillp,
    const float* __restrict__ Wallb, const float* __restrict__ Uallb,
    float* __restrict__ cb,
    const float* __restrict__ tw, float* __restrict__ twt,
    const float* __restrict__ U, _Float16* __restrict__ uh,
    const float* __restrict__ Wall, const float* __restrict__ Wd,
    int4* __restrict__ AW,
    const float* __restrict__ emb, _Float16* __restrict__ eh)
{
    const int blk = blockIdx.x;
    const int t   = threadIdx.x;
    if (blk < 1) {
        if (t < 128) outv[t] = outb[t & 1];
    } else if (blk < 4097) {
        fillp[(blk - 1) * 256 + t] =
            int4{(int)SENT32, (int)SENT32, (int)SENT32, (int)SENT32};
    } else if (blk < 4098) {
        #pragma unroll
        for (int k = 0; k < 8; k++) {
            int i = t * 8 + k;
            cb[i] = Wallb[i] + Uallb[i];
        }
    } else if (blk < 4130) {
        int i2 = (blk - 4098) * 256 + t;
        #pragma unroll
        for (int k = 0; k < 4; k++) {
            int i = i2 * 4 + k;              // 0..32767
            twt[(i & 63) * 512 + (i >> 6)] = tw[i];
        }
    } else if (blk < 5154) {
        int i = (blk - 4130) * 256 + t;      // 0..262143 float4 groups
        float4 v = ((const float4*)U)[i];
        union { _Float16 h[4]; unsigned long long u; } pk;
        pk.h[0] = (_Float16)v.x; pk.h[1] = (_Float16)v.y;
        pk.h[2] = (_Float16)v.z; pk.h[3] = (_Float16)v.w;
        ((unsigned long long*)uh)[i] = pk.u;
    } else if (blk < 5922) {
        int i = (blk - 5154) * 256 + t;      // 0..196607
        int lane = i & 63;  int r = i >> 6;
        int kt = r & 15;    r >>= 4;
        int tile = r % 3;   r /= 3;
        int w = r & 7;      int m = r >> 3;
        int row16 = lane & 15, quad = lane >> 4;
        int q = tile * 2 + (row16 >> 3);
        int d = m * 64 + w * 8 + (row16 & 7);
        int k0 = kt * 32 + quad * 8;
        union { _Float16 h[8]; int4 v; } u;
        const float* src = nullptr;
        if (q < 4)       src = Wall + (size_t)(q * 512 + d) * 512 + k0;
        else if (q == 4) src = Wd   + (size_t)d * 512 + k0;
        #pragma unroll
        for (int j = 0; j < 8; j++) u.h[j] = src ? (_Float16)src[j] : (_Float16)0.f;
        AW[i] = u.v;
    } else {
        int i = (blk - 5922) * 256 + t;      // pair index, 0..5120255
        float2 v = ((const float2*)emb)[i];
        unsigned short hx = __builtin_bit_cast(unsigned short, (_Float16)v.x);
        unsigned short hy = __builtin_bit_cast(unsigned short, (_Float16)v.y);
        ((unsigned*)eh)[i] = (unsigned)hx | ((unsigned)hy << 16);
    }
}

// ---------------- embedding gather-sum (fp16 table) -> x fp16 ----------------
__global__ void k_embed2(const _Float16* __restrict__ embh, const int* __restrict__ seqs,
                         _Float16* __restrict__ xh)
{
    int bs = blockIdx.x;           // b*S + s
    int t  = threadIdx.x;          // 256 threads, 2 halves each
    __shared__ int rows[32];
    if (t < 32) {
        int r = seqs[(size_t)bs * C_ + t];
        rows[t] = (r < 0) ? V_ : r;
    }
    __syncthreads();
    float ax = 0.f, ay = 0.f;
    #pragma unroll 4
    for (int c = 0; c < C_; c++) {
        unsigned v = *(const unsigned*)(embh + (size_t)rows[c] * D_ + 2 * t);
        ax += (float)__builtin_bit_cast(_Float16, (unsigned short)v);
        ay += (float)__builtin_bit_cast(_Float16, (unsigned short)(v >> 16));
    }
    unsigned short hx = __builtin_bit_cast(unsigned short, (_Float16)ax);
    unsigned short hy = __builtin_bit_cast(unsigned short, (_Float16)ay);
    *(unsigned*)(xh + (size_t)bs * D_ + 2 * t) = (unsigned)hx | ((unsigned)hy << 16);
}

// ---------------- time feature: 16 bs per block, thread-per-d ----------------
__global__ __launch_bounds__(512) void k_tf2(
    const float* __restrict__ stime, const float* __restrict__ selw,
    const float* __restrict__ selb, const float* __restrict__ twT,
    const float* __restrict__ timeb, _Float16* __restrict__ tf)
{
    int bb = blockIdx.x;           // covers bs = bb*16 .. bb*16+15
    int t  = threadIdx.x;          // 512
    __shared__ float s1[16][64];
    for (int idx = t; idx < 1024; idx += 512) {
        int bl = idx >> 6, j = idx & 63;
        float tv = stime[bb * 16 + bl] * (1.0f / 180.0f);
        float u  = tv * selw[j] + selb[j];
        s1[bl][j] = 1.0f - tanhf(u * u);
    }
    __syncthreads();
    int d = t;
    float acc[16];
    float tb = timeb[d];
    #pragma unroll
    for (int l = 0; l < 16; l++) acc[l] = tb;
    for (int j = 0; j < 64; j++) {
        float wj = twT[j * 512 + d];
        #pragma unroll
        for (int l = 0; l < 16; l++) acc[l] = fmaf(s1[l][j], wj, acc[l]);
    }
    #pragma unroll
    for (int l = 0; l < 16; l++)
        tf[(size_t)(bb * 16 + l) * 512 + d] = (_Float16)acc[l];
}

// ---------------- ux GEMM v3: m97-style LDS-staged, 128x128 tile, BK=64 --------
// 256 thr (4 waves, 2x2 wave grid, 64x64 wave tiles). global_load_lds width=16.
// LDS k8-column XOR-swizzled by (row&7): staging stays wave-uniform-base+lane*16,
// consumer ds_read_b128 spreads banks (2-way only, free).
__device__ __forceinline__ void stage16(const _Float16* g, _Float16* l)
{
#if __has_builtin(__builtin_amdgcn_global_load_lds)
    __builtin_amdgcn_global_load_lds((const AS1 void*)g, (AS3 void*)l, 16, 0, 0);
#else
    *(int4*)l = *(const int4*)g;
#endif
}

__global__ __launch_bounds__(256, 4) void k_gemm3(const _Float16* __restrict__ A,
                                                  const _Float16* __restrict__ Bm,
                                                  _Float16* __restrict__ Cg)
{
    __shared__ __align__(16) _Float16 As[128 * 64];
    __shared__ __align__(16) _Float16 Bs[128 * 64];
    const int t = threadIdx.x;
    const int w = t >> 6, lane = t & 63;
    const int wm = w & 1, wn = w >> 1;
    const int m0 = blockIdx.y * 128, n0 = blockIdx.x * 128;
    const int r16 = lane & 15, quad = lane >> 4;

    // staging role: wave w round r covers rows r*32 + w*8 + lane/8
    const int srow = w * 8 + (lane >> 3);
    const int k8g  = (lane & 7) ^ ((lane >> 3) & 7);   // swizzled global k8
    const _Float16* ga = A  + (size_t)(m0 + srow) * 512 + k8g * 8;
    const _Float16* gb = Bm + (size_t)(n0 + srow) * 512 + k8g * 8;
    _Float16* la = As + srow * 64 + (lane & 7) * 8;    // = As + w*512 + lane*8 elems
    _Float16* lb = Bs + srow * 64 + (lane & 7) * 8;

    f32x4 acc[4][4] = {};
    for (int k0 = 0; k0 < 512; k0 += 64) {
        __syncthreads();               // prior LDS consumers done
        #pragma unroll
        for (int r = 0; r < 4; r++) {
            stage16(ga + k0 + (size_t)r * 32 * 512, la + r * 32 * 64);
            stage16(gb + k0 + (size_t)r * 32 * 512, lb + r * 32 * 64);
        }
        __syncthreads();               // staging drained (vmcnt0 via barrier)
        #pragma unroll
        for (int sub = 0; sub < 2; sub++) {
            f16x8 af[4], bf[4];
            const int ksl = ((sub * 4 + quad) ^ (r16 & 7)) * 8;
            #pragma unroll
            for (int i = 0; i < 4; i++) {
                af[i] = *(const f16x8*)(As + (wm * 64 + i * 16 + r16) * 64 + ksl);
                bf[i] = *(const f16x8*)(Bs + (wn * 64 + i * 16 + r16) * 64 + ksl);
            }
            #pragma unroll
            for (int i = 0; i < 4; i++)
                #pragma unroll
                for (int j = 0; j < 4; j++)
                    acc[i][j] = __builtin_amdgcn_mfma_f32_16x16x32_f16(
                                    af[i], bf[j], acc[i][j], 0, 0, 0);
        }
    }
    // epilogue: C/D layout col=lane&15, row=quad*4+reg
    #pragma unroll
    for (int i = 0; i < 4; i++)
        #pragma unroll
        for (int j = 0; j < 4; j++) {
            int row = m0 + wm * 64 + i * 16 + quad * 4;
            int col = n0 + wn * 64 + j * 16 + r16;
            _Float16* cp = Cg + (size_t)row * 2048 + col;
            #pragma unroll
            for (int rg = 0; rg < 4; rg++)
                cp[(size_t)rg * 2048] = (_Float16)acc[i][j][rg];
        }
}

// ---------------- fast transcendentals (v_exp + v_rcp) ----------------
__device__ __forceinline__ float fsigm(float x)
{
    return __builtin_amdgcn_rcpf(1.f + __expf(-x));
}
__device__ __forceinline__ float ftanh(float x)
{
    return 1.f - 2.f * __builtin_amdgcn_rcpf(1.f + __expf(2.f * x));
}

// ---------------- recurrence: MFMA GEMV, weights in A-frag VGPRs -------------
// (round-7 structure, proven at ~293 us; epilogue now atomicAdds into d_out,
// which k_prep_fused SEG0 pre-initialized with the output bias)
__global__ __launch_bounds__(512, 2) void k_rnn7(
    const int4* __restrict__ AW,
    const float* __restrict__ cbv, const float* __restrict__ wdb,
    const _Float16* __restrict__ ux, const _Float16* __restrict__ tf,
    const float* __restrict__ outw,
    float* __restrict__ out,
    unsigned long long* __restrict__ xb64)
{
    const int t    = threadIdx.x;
    const int gid  = blockIdx.x >> 3;
    const int m    = blockIdx.x & 7;
    const int b0   = gid * 2;
    const int w    = t >> 6;           // wave id: consumer of member w, owner of d-octet w*8
    const int lane = t & 63;
    const int col  = lane & 15;
    const int quad = lane >> 4;

    int4 Af[48];
    {
        const int4* src = AW + (size_t)(m * 8 + w) * 3072;
        #pragma unroll
        for (int i = 0; i < 48; i++) Af[i] = src[i * 64 + lane];
    }

    __shared__ __align__(16) _Float16 xstg[4 * 544];   // 4 streams, 64B inter-pad
    __shared__ __align__(16) float cmat[8][4][48];
    __shared__ float pstg[2][64];

    const bool act = (lane < 16);
    const int  pb  = lane >> 3;
    const int  pj  = lane & 7;
    const int  dl  = w * 8 + pj;
    const int  d   = m * 64 + dl;

    float cbf = 0, cbi = 0, cbo = 0, cbc = 0, bdv = 0;
    if (act) {
        cbf = cbv[d]; cbi = cbv[512 + d]; cbo = cbv[1024 + d]; cbc = cbv[1536 + d];
        bdv = wdb[d];
    }
    float c_reg = 0.f, pool = -1e30f;
    const int dw = w * 64 + lane;

    for (int s = 0; s < S_; s++) {
        float uf = 0, ui = 0, uo = 0, uc = 0, tv = 0;
        if (act) {
            size_t bs = (size_t)(b0 + pb) * S_ + s;
            const _Float16* up = ux + bs * 2048 + d;
            uf = (float)up[0];    ui = (float)up[512];
            uo = (float)up[1024]; uc = (float)up[1536];
            tv = (float)tf[bs * 512 + d];
        }

        unsigned long long val = 0ull;
        if (s > 0) {
            const unsigned long long* src =
                xb64 + (((size_t)s * 32 + gid) * 8 + w) * 64 + lane;
            int tries = 0;
            for (;;) {
                val = __hip_atomic_load(src, __ATOMIC_RELAXED,
                                        __HIP_MEMORY_SCOPE_AGENT);
                if ((unsigned)val != SENT32 && (unsigned)(val >> 32) != SENT32)
                    break;
                if (++tries > (1 << 22)) break;   // safety valve
            }
        }
        __syncthreads();              // B2: prior step's xstg readers done
        xstg[0 * 544 + dw] = __builtin_bit_cast(_Float16, (unsigned short)(val));
        xstg[2 * 544 + dw] = __builtin_bit_cast(_Float16, (unsigned short)(val >> 16));
        xstg[1 * 544 + dw] = __builtin_bit_cast(_Float16, (unsigned short)(val >> 32));
        xstg[3 * 544 + dw] = __builtin_bit_cast(_Float16, (unsigned short)(val >> 48));
        __syncthreads();              // B1: staging visible

        f32x4 a0 = {0, 0, 0, 0}, a1 = {0, 0, 0, 0}, a2 = {0, 0, 0, 0};
        #pragma unroll
        for (int kt = 0; kt < 16; kt++) {
            f16x8 b = {};
            if (col < 4)
                b = *(const f16x8*)(xstg + col * 544 + kt * 32 + quad * 8);
            a0 = __builtin_amdgcn_mfma_f32_16x16x32_f16(
                     __builtin_bit_cast(f16x8, Af[kt]),      b, a0, 0, 0, 0);
            a1 = __builtin_amdgcn_mfma_f32_16x16x32_f16(
                     __builtin_bit_cast(f16x8, Af[16 + kt]), b, a1, 0, 0, 0);
            a2 = __builtin_amdgcn_mfma_f32_16x16x32_f16(
                     __builtin_bit_cast(f16x8, Af[32 + kt]), b, a2, 0, 0, 0);
        }

        if (col < 4) {
            *(f32x4*)&cmat[w][col][ 0 + quad * 4] = a0;
            *(f32x4*)&cmat[w][col][16 + quad * 4] = a1;
            *(f32x4*)&cmat[w][col][32 + quad * 4] = a2;
        }

        if (act) {
            float f_  = cmat[w][pb][ 0 + pj];
            float i_  = cmat[w][pb][ 8 + pj];
            float o_  = cmat[w][pb][16 + pj];
            float g_  = cmat[w][pb][24 + pj];
            float wd_ = cmat[w][2 + pb][32 + pj];
            float gf = fsigm(f_ + cbf + uf);
            float gi = fsigm(i_ + cbi + ui);
            float go = fsigm(o_ + cbo + uo);
            float gc = fsigm(g_ + cbc + uc);
            float cs1  = ftanh(wd_ + bdv);
            float cadj = c_reg - cs1 + cs1 * tv;
            float cn   = gf * cadj + gi * gc;
            float hn   = go * ftanh(cn);
            c_reg = cn;
            pool  = fmaxf(pool, hn);
            unsigned hh = __builtin_bit_cast(unsigned short, (_Float16)hn);
            unsigned cc = __builtin_bit_cast(unsigned short, (_Float16)cn);
            unsigned pk = hh | (cc << 16);
            unsigned other = __shfl(pk, lane + 8);
            if (pb == 0 && s != S_ - 1) {
                unsigned long long ov =
                    (unsigned long long)pk | ((unsigned long long)other << 32);
                unsigned long long* dst =
                    xb64 + (((size_t)(s + 1) * 32 + gid) * 8 + m) * 64 + dl;
                __hip_atomic_store(dst, ov, __ATOMIC_RELAXED,
                                   __HIP_MEMORY_SCOPE_AGENT);
            }
        }
    }

    // pooled epilogue -> atomicAdd into bias-initialized d_out
    if (act) pstg[pb][dl] = pool;
    __syncthreads();
    if (t < 128) {
        int b = t >> 6, l = t & 63;
        float pv = pstg[b][l];
        int dg = m * 64 + l;
        float p0 = pv * outw[dg], p1 = pv * outw[512 + dg];
        #pragma unroll
        for (int off = 32; off > 0; off >>= 1) {
            p0 += __shfl_down(p0, off);
            p1 += __shfl_down(p1, off);
        }
        if (l == 0) {
            atomicAdd(&out[2 * (b0 + b)],     p0);
            atomicAdd(&out[2 * (b0 + b) + 1], p1);
        }
    }
}

// ---------------- launch ----------------
extern "C" void kernel_launch(void* const* d_in, const int* in_sizes, int n_in,
                              void* d_out, int out_size, void* d_ws, size_t ws_size,
                              hipStream_t stream)
{
    const float* emb   = (const float*)d_in[0];
    const float* Wall  = (const float*)d_in[1];
    const float* Wallb = (const float*)d_in[2];
    const float* Uall  = (const float*)d_in[3];
    const float* Uallb = (const float*)d_in[4];
    const float* Wdw   = (const float*)d_in[5];
    const float* Wdb   = (const float*)d_in[6];
    const float* selw  = (const float*)d_in[7];
    const float* selb  = (const float*)d_in[8];
    const float* timew = (const float*)d_in[9];
    const float* timeb = (const float*)d_in[10];
    const float* outw  = (const float*)d_in[11];
    const float* outb  = (const float*)d_in[12];
    const float* stime = (const float*)d_in[13];
    const int*   seqs  = (const int*)d_in[14];
    float* out = (float*)d_out;
    char*  ws  = (char*)d_ws;

    _Float16* xh   = (_Float16*)(ws + OFF_XH);
    _Float16* uh   = (_Float16*)(ws + OFF_UH);
    int4*     aw   = (int4*)(ws + OFF_AW);
    float*    cbp  = (float*)(ws + OFF_CB);
    float*    twt  = (float*)(ws + OFF_TWT);
    _Float16* eh   = (_Float16*)(ws + OFF_EMBH);
    _Float16* tfp  = (_Float16*)(ws + OFF_TF);
    _Float16* uxp  = (_Float16*)(ws + OFF_UX);
    unsigned long long* xb = (unsigned long long*)(ws + OFF_XB2);

    k_prep_fused<<<25923, 256, 0, stream>>>(
        outb, out, (int4*)(ws + OFF_XB2),
        Wallb, Uallb, cbp,
        timew, twt,
        Uall, uh,
        Wall, Wdw, aw,
        emb, eh);
    k_embed2 <<<B_ * S_, 256, 0, stream>>>(eh, seqs, xh);
    k_tf2    <<<512,     512, 0, stream>>>(stime, selw, selb, twt, timeb, tfp);
    k_gemm3  <<<dim3(16, 64), 256, 0, stream>>>(xh, uh, uxp);
    k_rnn7   <<<256,     512, 0, stream>>>(aw, cbp, Wdb, uxp, tfp, outw, out, xb);
}